// Round 1
// baseline (1351.970 us; speedup 1.0000x reference)
//
#include <hip/hip_runtime.h>
#include <math.h>

// ---------------------------------------------------------------- CSR build
__global__ void k_fill_ones(int* __restrict__ f, int n) {
    int i = blockIdx.x * 256 + threadIdx.x;
    if (i < n) f[i] = 1;
}
__global__ void k_count(const int* __restrict__ dst, int* __restrict__ f, int e) {
    int i = blockIdx.x * 256 + threadIdx.x;
    if (i < e) atomicAdd(&f[dst[i]], 1);
}
__global__ __launch_bounds__(256) void k_scan1(const int* __restrict__ cnt, int* __restrict__ bsum, int n) {
    __shared__ int sd[256];
    int base = blockIdx.x * 1024, t = threadIdx.x;
    int s = 0;
#pragma unroll
    for (int i = 0; i < 4; ++i) {
        int idx = base + t * 4 + i;
        if (idx < n) s += cnt[idx];
    }
    sd[t] = s; __syncthreads();
    for (int o = 128; o; o >>= 1) {
        if (t < o) sd[t] += sd[t + o];
        __syncthreads();
    }
    if (t == 0) bsum[blockIdx.x] = sd[0];
}
__global__ void k_scan2(int* __restrict__ bsum, int nb) {
    __shared__ int sd[128];
    int t = threadIdx.x;
    int v = (t < nb) ? bsum[t] : 0;
    sd[t] = v; __syncthreads();
    for (int o = 1; o < 128; o <<= 1) {
        int u = (t >= o) ? sd[t - o] : 0;
        __syncthreads();
        sd[t] += u;
        __syncthreads();
    }
    if (t < nb) bsum[t] = sd[t] - v;  // exclusive
}
__global__ __launch_bounds__(256) void k_scan3(const int* __restrict__ cnt, const int* __restrict__ bsum,
                                               int* __restrict__ rp, int n, int total) {
    __shared__ int sd[256];
    int base = blockIdx.x * 1024, t = threadIdx.x;
    int v[4]; int s = 0;
#pragma unroll
    for (int i = 0; i < 4; ++i) {
        int idx = base + t * 4 + i;
        v[i] = (idx < n) ? cnt[idx] : 0;
        s += v[i];
    }
    sd[t] = s; __syncthreads();
    for (int o = 1; o < 256; o <<= 1) {
        int u = (t >= o) ? sd[t - o] : 0;
        __syncthreads();
        sd[t] += u;
        __syncthreads();
    }
    int excl = sd[t] - s + bsum[blockIdx.x];
#pragma unroll
    for (int i = 0; i < 4; ++i) {
        int idx = base + t * 4 + i;
        if (idx < n) rp[idx] = excl;
        excl += v[i];
    }
    if (blockIdx.x == 0 && t == 0) rp[n] = total;
}
__global__ void k_zero_i(int* __restrict__ f, int n) {
    int i = blockIdx.x * 256 + threadIdx.x;
    if (i < n) f[i] = 0;
}
__global__ void k_scatter(const int* __restrict__ src, const int* __restrict__ dst,
                          const int* __restrict__ rp, int* __restrict__ fill, int* __restrict__ col,
                          int e, int n) {
    int i = blockIdx.x * 256 + threadIdx.x;
    int tot = e + n;
    if (i >= tot) return;
    int s, d;
    if (i < e) { s = src[i]; d = dst[i]; }
    else       { s = d = i - e; }               // self loops
    int p = rp[d] + atomicAdd(&fill[d], 1);
    col[p] = s;
}

// ---------------------------------------------------------------- GEMM 128xK=128 (+ fused attention-logit epilogue)
// ATT = 0: out = A@W + bias.  ATT = 4 / 1: out = A@W; al_s/al_d = per-head dots with att vectors.
template <int ATT>
__global__ __launch_bounds__(256) void k_gemm(
    const float* __restrict__ A, const float* __restrict__ W,
    const float* __restrict__ bias, float* __restrict__ out,
    const float* __restrict__ atts, const float* __restrict__ attd,
    float* __restrict__ als, float* __restrict__ ald,
    int nrows, int ntiles)
{
    __shared__ float Ws[128 * 128];
    __shared__ float As[64][129];
    __shared__ float redS[4][16][4];
    __shared__ float redD[4][16][4];
    const int t = threadIdx.x;
    {
        const float4* W4 = (const float4*)W;
        float4* S4 = (float4*)Ws;
#pragma unroll
        for (int i = 0; i < 16; ++i) S4[t + i * 256] = W4[t + i * 256];
    }
    const int rg = t & 15, cg = t >> 4;
    const int r4 = rg * 4, c0 = cg * 8;
    const int wv = t >> 6;

    float bloc[8];
    if (ATT == 0) {
#pragma unroll
        for (int j = 0; j < 8; ++j) bloc[j] = bias[c0 + j];
    }
    float avs[8], avd[8];
    if (ATT > 0) {
#pragma unroll
        for (int j = 0; j < 8; ++j) { avs[j] = atts[c0 + j]; avd[j] = attd[c0 + j]; }
    }

    for (int tile = blockIdx.x; tile < ntiles; tile += gridDim.x) {
        const int row0 = tile * 64;
        __syncthreads();
#pragma unroll
        for (int i = 0; i < 8; ++i) {
            int f = t + i * 256, r = f >> 5, kk = (f & 31) << 2;
            float4 v = make_float4(0.f, 0.f, 0.f, 0.f);
            int row = row0 + r;
            if (row < nrows) v = *(const float4*)&A[(size_t)row * 128 + kk];
            As[r][kk] = v.x; As[r][kk + 1] = v.y; As[r][kk + 2] = v.z; As[r][kk + 3] = v.w;
        }
        __syncthreads();

        float acc[4][8] = {};
#pragma unroll 8
        for (int k = 0; k < 128; ++k) {
            float a0 = As[r4 + 0][k], a1 = As[r4 + 1][k], a2 = As[r4 + 2][k], a3 = As[r4 + 3][k];
            float w[8];
            *(float4*)&w[0] = *(const float4*)&Ws[k * 128 + c0];
            *(float4*)&w[4] = *(const float4*)&Ws[k * 128 + c0 + 4];
#pragma unroll
            for (int j = 0; j < 8; ++j) {
                acc[0][j] += a0 * w[j];
                acc[1][j] += a1 * w[j];
                acc[2][j] += a2 * w[j];
                acc[3][j] += a3 * w[j];
            }
        }
        // store
#pragma unroll
        for (int r = 0; r < 4; ++r) {
            int row = row0 + r4 + r;
            if (row < nrows) {
                float o[8];
#pragma unroll
                for (int j = 0; j < 8; ++j) o[j] = acc[r][j] + (ATT == 0 ? bloc[j] : 0.f);
                *(float4*)&out[(size_t)row * 128 + c0]     = *(float4*)&o[0];
                *(float4*)&out[(size_t)row * 128 + c0 + 4] = *(float4*)&o[4];
            }
        }
        if (ATT > 0) {
            float ps[4], pd[4];
#pragma unroll
            for (int r = 0; r < 4; ++r) {
                float s = 0.f, d = 0.f;
#pragma unroll
                for (int j = 0; j < 8; ++j) { s += acc[r][j] * avs[j]; d += acc[r][j] * avd[j]; }
                ps[r] = s; pd[r] = d;
            }
#pragma unroll
            for (int r = 0; r < 4; ++r) {
                ps[r] += __shfl_xor(ps[r], 16); ps[r] += __shfl_xor(ps[r], 32);
                pd[r] += __shfl_xor(pd[r], 16); pd[r] += __shfl_xor(pd[r], 32);
            }
            if (ATT == 4) {
                if ((t & 48) == 0) {
#pragma unroll
                    for (int r = 0; r < 4; ++r) {
                        int row = row0 + r4 + r;
                        if (row < nrows) { als[row * 4 + wv] = ps[r]; ald[row * 4 + wv] = pd[r]; }
                    }
                }
            } else {
                if ((t & 48) == 0) {
#pragma unroll
                    for (int r = 0; r < 4; ++r) { redS[wv][rg][r] = ps[r]; redD[wv][rg][r] = pd[r]; }
                }
                __syncthreads();
                if (t < 64) {
                    int rr = t >> 2, j = t & 3;
                    float s = redS[0][rr][j] + redS[1][rr][j] + redS[2][rr][j] + redS[3][rr][j];
                    float d = redD[0][rr][j] + redD[1][rr][j] + redD[2][rr][j] + redD[3][rr][j];
                    int row = row0 + rr * 4 + j;
                    if (row < nrows) { als[row] = s; ald[row] = d; }
                }
            }
        }
    }
}

// ---------------------------------------------------------------- GAT aggregation: one wave per dst node, online softmax
template <int H>
__global__ __launch_bounds__(256) void k_agg(
    const int* __restrict__ rp, const int* __restrict__ col,
    const float* __restrict__ als, const float* __restrict__ ald_,
    const float* __restrict__ xs, const float* __restrict__ bias,
    const float* __restrict__ bg, const float* __restrict__ bb,
    const float* __restrict__ bm, const float* __restrict__ bv,
    float* __restrict__ h, int n)
{
    int node = blockIdx.x * 4 + (threadIdx.x >> 6);
    if (node >= n) return;
    int l = threadIdx.x & 63;
    int hl = (H == 4) ? (l >> 4) : 0;
    int c0 = l * 2;
    float ad = ald_[node * H + hl];
    float m = -INFINITY, z = 0.f, a0 = 0.f, a1 = 0.f;
    int jb = rp[node], je = rp[node + 1];
    for (int j = jb; j < je; ++j) {
        int s = col[j];
        float lg = als[s * H + hl] + ad;
        lg = lg > 0.f ? lg : 0.2f * lg;          // leaky_relu 0.2
        float mn = fmaxf(m, lg);
        float sc = __expf(m - mn);
        float p  = __expf(lg - mn);
        const float2 x = *(const float2*)&xs[(size_t)s * 128 + c0];
        z  = z * sc + p;
        a0 = a0 * sc + p * x.x;
        a1 = a1 * sc + p * x.y;
        m = mn;
    }
    float inv = 1.f / (z + 1e-16f);
    float y0 = a0 * inv + bias[c0];
    float y1 = a1 * inv + bias[c0 + 1];
    y0 = (y0 - bm[c0])     * (bg[c0]     / sqrtf(bv[c0]     + 1e-5f)) + bb[c0];
    y1 = (y1 - bm[c0 + 1]) * (bg[c0 + 1] / sqrtf(bv[c0 + 1] + 1e-5f)) + bb[c0 + 1];
    y0 = y0 > 0.f ? y0 : expm1f(y0);             // ELU
    y1 = y1 > 0.f ? y1 : expm1f(y1);
    float2 hv = *(const float2*)&h[(size_t)node * 128 + c0];
    hv.x += y0; hv.y += y1;
    *(float2*)&h[(size_t)node * 128 + c0] = hv;  // residual, in-place (own row only)
}

// ---------------------------------------------------------------- readout
__global__ __launch_bounds__(256) void k_scores(
    const float* __restrict__ h, const float* __restrict__ w1, const float* __restrict__ b1,
    const float* __restrict__ w2, const float* __restrict__ b2,
    float* __restrict__ scores, int n)
{
    int node = blockIdx.x * 4 + (threadIdx.x >> 6);
    if (node >= n) return;
    int l = threadIdx.x & 63;
    const float* hr = &h[(size_t)node * 128];
    float acc = b1[l];
#pragma unroll 8
    for (int k = 0; k < 128; k += 4) {
        float4 hv = *(const float4*)&hr[k];      // wave-uniform broadcast
        acc += hv.x * w1[k * 64 + l] + hv.y * w1[(k + 1) * 64 + l]
             + hv.z * w1[(k + 2) * 64 + l] + hv.w * w1[(k + 3) * 64 + l];
    }
    float sc = tanhf(acc) * w2[l];
#pragma unroll
    for (int off = 32; off; off >>= 1) sc += __shfl_xor(sc, off);
    if (l == 0) scores[node] = sc + b2[0];
}
__global__ void k_graph_ptr(const int* __restrict__ batch, int* __restrict__ gptr, int n, int B) {
    int i = blockIdx.x * 256 + threadIdx.x;
    if (i >= n) return;
    int b = batch[i];
    int bp = (i == 0) ? -1 : batch[i - 1];
    for (int g = bp + 1; g <= b; ++g) gptr[g] = i;
    if (i == n - 1)
        for (int g = b + 1; g <= B; ++g) gptr[g] = n;
}
__global__ __launch_bounds__(256) void k_graph_mz(const int* __restrict__ gptr, const float* __restrict__ scores,
                                                  float* __restrict__ gmax, float* __restrict__ gz, int B) {
    int g = blockIdx.x * 4 + (threadIdx.x >> 6);
    if (g >= B) return;
    int l = threadIdx.x & 63;
    int s0 = gptr[g], s1 = gptr[g + 1];
    float m = -INFINITY;
    for (int i = s0 + l; i < s1; i += 64) m = fmaxf(m, scores[i]);
#pragma unroll
    for (int off = 32; off; off >>= 1) m = fmaxf(m, __shfl_xor(m, off));
    float z = 0.f;
    for (int i = s0 + l; i < s1; i += 64) z += __expf(scores[i] - m);
#pragma unroll
    for (int off = 32; off; off >>= 1) z += __shfl_xor(z, off);
    if (l == 0) { gmax[g] = m; gz[g] = z; }
}
__global__ void k_att(const int* __restrict__ batch, const float* __restrict__ scores,
                      const float* __restrict__ gmax, const float* __restrict__ gz,
                      float* __restrict__ att, int n) {
    int i = blockIdx.x * 256 + threadIdx.x;
    if (i >= n) return;
    int b = batch[i];
    att[i] = __expf(scores[i] - gmax[b]) / gz[b];
}
__global__ __launch_bounds__(128) void k_emb(const int* __restrict__ gptr, const float* __restrict__ att,
                                             const float* __restrict__ h, float* __restrict__ emb) {
    int g = blockIdx.x, c = threadIdx.x;
    int s0 = gptr[g], s1 = gptr[g + 1];
    float acc = 0.f;
    for (int i = s0; i < s1; ++i) acc += att[i] * h[(size_t)i * 128 + c];
    emb[g * 128 + c] = acc;
}

// ---------------------------------------------------------------- launch
extern "C" void kernel_launch(void* const* d_in, const int* in_sizes, int n_in,
                              void* d_out, int out_size, void* d_ws, size_t ws_size,
                              hipStream_t stream)
{
    const float* x            = (const float*)d_in[0];
    const int*   eidx         = (const int*)d_in[1];
    const int*   batch        = (const int*)d_in[2];
    const float* W_in         = (const float*)d_in[3];
    const float* b_in         = (const float*)d_in[4];
    const float* lin_w        = (const float*)d_in[5];
    const float* att_src      = (const float*)d_in[6];
    const float* att_dst      = (const float*)d_in[7];
    const float* conv_b       = (const float*)d_in[8];
    const float* lin_w_last   = (const float*)d_in[9];
    const float* att_src_last = (const float*)d_in[10];
    const float* att_dst_last = (const float*)d_in[11];
    const float* b_last       = (const float*)d_in[12];
    const float* bn_g         = (const float*)d_in[13];
    const float* bn_b         = (const float*)d_in[14];
    const float* bn_m         = (const float*)d_in[15];
    const float* bn_v         = (const float*)d_in[16];
    const float* ro_w1        = (const float*)d_in[17];
    const float* ro_b1        = (const float*)d_in[18];
    const float* ro_w2        = (const float*)d_in[19];
    const float* ro_b2        = (const float*)d_in[20];

    const int N = in_sizes[0] / 128;
    const int E = in_sizes[1] / 2;
    const int B = 512;
    const int* esrc = eidx;
    const int* edst = eidx + E;

    char* wsp = (char*)d_ws;
    size_t off = 0;
    auto alloc = [&](size_t bytes) -> void* {
        void* p = wsp + off;
        off += (bytes + 511) & ~(size_t)511;
        return p;
    };
    float* h      = (float*)alloc((size_t)N * 128 * 4);
    float* xs     = (float*)alloc((size_t)N * 128 * 4);
    float* als    = (float*)alloc((size_t)N * 4 * 4);
    float* ald    = (float*)alloc((size_t)N * 4 * 4);
    float* scores = (float*)alloc((size_t)N * 4);
    int*   rp     = (int*)alloc((size_t)(N + 1) * 4);
    int*   col    = (int*)alloc((size_t)(E + N) * 4);
    int*   fill   = (int*)alloc((size_t)N * 4);
    int*   bsum   = (int*)alloc(4096);
    int*   gptr   = (int*)alloc((size_t)(B + 1) * 4);
    float* gmax   = (float*)alloc((size_t)B * 4);
    float* gz     = (float*)alloc((size_t)B * 4);
    (void)ws_size; (void)n_in; (void)out_size;

    float* emb = (float*)d_out;
    float* att = (float*)d_out + (size_t)B * 128;

    const int nb = (N + 1023) / 1024;
    hipLaunchKernelGGL(k_fill_ones, dim3((N + 255) / 256), dim3(256), 0, stream, fill, N);
    hipLaunchKernelGGL(k_count, dim3((E + 255) / 256), dim3(256), 0, stream, edst, fill, E);
    hipLaunchKernelGGL(k_scan1, dim3(nb), dim3(256), 0, stream, fill, bsum, N);
    hipLaunchKernelGGL(k_scan2, dim3(1), dim3(128), 0, stream, bsum, nb);
    hipLaunchKernelGGL(k_scan3, dim3(nb), dim3(256), 0, stream, fill, bsum, rp, N, E + N);
    hipLaunchKernelGGL(k_zero_i, dim3((N + 255) / 256), dim3(256), 0, stream, fill, N);
    hipLaunchKernelGGL(k_scatter, dim3((E + N + 255) / 256), dim3(256), 0, stream, esrc, edst, rp, fill, col, E, N);

    const int ntiles = (N + 63) / 64;
    hipLaunchKernelGGL((k_gemm<0>), dim3(512), dim3(256), 0, stream,
                       x, W_in, b_in, h, (const float*)nullptr, (const float*)nullptr,
                       (float*)nullptr, (float*)nullptr, N, ntiles);
    for (int i = 0; i < 2; ++i) {
        hipLaunchKernelGGL((k_gemm<4>), dim3(512), dim3(256), 0, stream,
                           h, lin_w + (size_t)i * 16384, (const float*)nullptr, xs,
                           att_src + i * 128, att_dst + i * 128, als, ald, N, ntiles);
        hipLaunchKernelGGL((k_agg<4>), dim3((N + 3) / 4), dim3(256), 0, stream,
                           rp, col, als, ald, xs, conv_b + i * 128,
                           bn_g + i * 128, bn_b + i * 128, bn_m + i * 128, bn_v + i * 128, h, N);
    }
    hipLaunchKernelGGL((k_gemm<1>), dim3(512), dim3(256), 0, stream,
                       h, lin_w_last, (const float*)nullptr, xs,
                       att_src_last, att_dst_last, als, ald, N, ntiles);
    hipLaunchKernelGGL((k_agg<1>), dim3((N + 3) / 4), dim3(256), 0, stream,
                       rp, col, als, ald, xs, b_last,
                       bn_g + 256, bn_b + 256, bn_m + 256, bn_v + 256, h, N);

    hipLaunchKernelGGL(k_scores, dim3((N + 3) / 4), dim3(256), 0, stream,
                       h, ro_w1, ro_b1, ro_w2, ro_b2, scores, N);
    hipLaunchKernelGGL(k_graph_ptr, dim3((N + 255) / 256), dim3(256), 0, stream, batch, gptr, N, B);
    hipLaunchKernelGGL(k_graph_mz, dim3((B + 3) / 4), dim3(256), 0, stream, gptr, scores, gmax, gz, B);
    hipLaunchKernelGGL(k_att, dim3((N + 255) / 256), dim3(256), 0, stream, batch, scores, gmax, gz, att, N);
    hipLaunchKernelGGL(k_emb, dim3(B), dim3(128), 0, stream, gptr, att, h, emb);
}

// Round 2
// 1285.450 us; speedup vs baseline: 1.0517x; 1.0517x over previous
//
#include <hip/hip_runtime.h>
#include <math.h>
#include <stdint.h>

static __device__ __forceinline__ uint32_t f2bf(float x) {
    uint32_t u = __float_as_uint(x);
    return (u + 0x7fffu + ((u >> 16) & 1u)) >> 16;   // RNE, no NaN handling needed
}

// ---------------------------------------------------------------- CSR build
__global__ void k_fill_ones(int* __restrict__ f, int n) {
    int i = blockIdx.x * 256 + threadIdx.x;
    if (i < n) f[i] = 1;
}
__global__ void k_count(const int* __restrict__ dst, int* __restrict__ f, int e) {
    int i = blockIdx.x * 256 + threadIdx.x;
    if (i < e) atomicAdd(&f[dst[i]], 1);
}
__global__ __launch_bounds__(256) void k_scan1(const int* __restrict__ cnt, int* __restrict__ bsum, int n) {
    __shared__ int sd[256];
    int base = blockIdx.x * 1024, t = threadIdx.x;
    int s = 0;
#pragma unroll
    for (int i = 0; i < 4; ++i) {
        int idx = base + t * 4 + i;
        if (idx < n) s += cnt[idx];
    }
    sd[t] = s; __syncthreads();
    for (int o = 128; o; o >>= 1) {
        if (t < o) sd[t] += sd[t + o];
        __syncthreads();
    }
    if (t == 0) bsum[blockIdx.x] = sd[0];
}
__global__ void k_scan2(int* __restrict__ bsum, int nb) {
    __shared__ int sd[128];
    int t = threadIdx.x;
    int v = (t < nb) ? bsum[t] : 0;
    sd[t] = v; __syncthreads();
    for (int o = 1; o < 128; o <<= 1) {
        int u = (t >= o) ? sd[t - o] : 0;
        __syncthreads();
        sd[t] += u;
        __syncthreads();
    }
    if (t < nb) bsum[t] = sd[t] - v;  // exclusive
}
__global__ __launch_bounds__(256) void k_scan3(const int* __restrict__ cnt, const int* __restrict__ bsum,
                                               int* __restrict__ rp, int n, int total) {
    __shared__ int sd[256];
    int base = blockIdx.x * 1024, t = threadIdx.x;
    int v[4]; int s = 0;
#pragma unroll
    for (int i = 0; i < 4; ++i) {
        int idx = base + t * 4 + i;
        v[i] = (idx < n) ? cnt[idx] : 0;
        s += v[i];
    }
    sd[t] = s; __syncthreads();
    for (int o = 1; o < 256; o <<= 1) {
        int u = (t >= o) ? sd[t - o] : 0;
        __syncthreads();
        sd[t] += u;
        __syncthreads();
    }
    int excl = sd[t] - s + bsum[blockIdx.x];
#pragma unroll
    for (int i = 0; i < 4; ++i) {
        int idx = base + t * 4 + i;
        if (idx < n) rp[idx] = excl;
        excl += v[i];
    }
    if (blockIdx.x == 0 && t == 0) rp[n] = total;
}
__global__ void k_zero_i(int* __restrict__ f, int n) {
    int i = blockIdx.x * 256 + threadIdx.x;
    if (i < n) f[i] = 0;
}
__global__ void k_scatter(const int* __restrict__ src, const int* __restrict__ dst,
                          const int* __restrict__ rp, int* __restrict__ fill, int* __restrict__ col,
                          int e, int n) {
    int i = blockIdx.x * 256 + threadIdx.x;
    int tot = e + n;
    if (i >= tot) return;
    int s, d;
    if (i < e) { s = src[i]; d = dst[i]; }
    else       { s = d = i - e; }               // self loops
    int p = rp[d] + atomicAdd(&fill[d], 1);
    col[p] = s;
}

// ---------------------------------------------------------------- GEMM 128x128 tile, 8x8 micro-tile
// ATT = 0: out(f32) = A@W + bias.  ATT = 4 / 1: out(bf16) = A@W; als/ald = per-head att dots (f32, from f32 acc).
template <int ATT, int OBF>
__global__ __launch_bounds__(256) void k_gemm(
    const float* __restrict__ A, const float* __restrict__ W,
    const float* __restrict__ bias, void* __restrict__ outv,
    const float* __restrict__ atts, const float* __restrict__ attd,
    float* __restrict__ als, float* __restrict__ ald,
    int nrows)
{
    __shared__ float Ws[128 * 128];   // 64 KB
    __shared__ float As[16][128];     // 8 KB, transposed chunk
    const int t = threadIdx.x;
    {
        const float4* W4 = (const float4*)W;
        float4* S4 = (float4*)Ws;
#pragma unroll
        for (int i = 0; i < 16; ++i) S4[t + i * 256] = W4[t + i * 256];
    }
    const int rg = t & 15, cg = t >> 4;
    const int r0 = rg * 8, c0 = cg * 8;
    const int wv = t >> 6;
    const int row0 = blockIdx.x * 128;

    float bloc[8], avs[8], avd[8];
    if (ATT == 0) {
#pragma unroll
        for (int j = 0; j < 8; ++j) bloc[j] = bias[c0 + j];
    } else {
#pragma unroll
        for (int j = 0; j < 8; ++j) { avs[j] = atts[c0 + j]; avd[j] = attd[c0 + j]; }
    }

    float acc[8][8] = {};
    for (int kc = 0; kc < 8; ++kc) {
        __syncthreads();
#pragma unroll
        for (int i = 0; i < 2; ++i) {
            int f = t * 2 + i;
            int r = f >> 2, kk = (f & 3) * 4;
            float4 v = make_float4(0.f, 0.f, 0.f, 0.f);
            int row = row0 + r;
            if (row < nrows) v = *(const float4*)&A[(size_t)row * 128 + kc * 16 + kk];
            As[kk + 0][r] = v.x; As[kk + 1][r] = v.y; As[kk + 2][r] = v.z; As[kk + 3][r] = v.w;
        }
        __syncthreads();
#pragma unroll
        for (int kk = 0; kk < 16; ++kk) {
            float a[8], w[8];
            *(float4*)&a[0] = *(const float4*)&As[kk][r0];
            *(float4*)&a[4] = *(const float4*)&As[kk][r0 + 4];
            *(float4*)&w[0] = *(const float4*)&Ws[(kc * 16 + kk) * 128 + c0];
            *(float4*)&w[4] = *(const float4*)&Ws[(kc * 16 + kk) * 128 + c0 + 4];
#pragma unroll
            for (int r = 0; r < 8; ++r)
#pragma unroll
                for (int j = 0; j < 8; ++j)
                    acc[r][j] += a[r] * w[j];
        }
    }

    // ---- store
    if (OBF) {
        uint16_t* out = (uint16_t*)outv;
#pragma unroll
        for (int r = 0; r < 8; ++r) {
            int row = row0 + r0 + r;
            if (row < nrows) {
                uint32_t up[4];
#pragma unroll
                for (int jj = 0; jj < 4; ++jj)
                    up[jj] = (f2bf(acc[r][2 * jj + 1]) << 16) | f2bf(acc[r][2 * jj]);
                *(uint4*)&out[(size_t)row * 128 + c0] = make_uint4(up[0], up[1], up[2], up[3]);
            }
        }
    } else {
        float* out = (float*)outv;
#pragma unroll
        for (int r = 0; r < 8; ++r) {
            int row = row0 + r0 + r;
            if (row < nrows) {
                float o[8];
#pragma unroll
                for (int j = 0; j < 8; ++j) o[j] = acc[r][j] + bloc[j];
                *(float4*)&out[(size_t)row * 128 + c0]     = *(float4*)&o[0];
                *(float4*)&out[(size_t)row * 128 + c0 + 4] = *(float4*)&o[4];
            }
        }
    }

    // ---- attention-logit epilogue
    if (ATT > 0) {
        float ps[8], pd[8];
#pragma unroll
        for (int r = 0; r < 8; ++r) {
            float s = 0.f, d = 0.f;
#pragma unroll
            for (int j = 0; j < 8; ++j) { s += acc[r][j] * avs[j]; d += acc[r][j] * avd[j]; }
            ps[r] = s; pd[r] = d;
        }
#pragma unroll
        for (int r = 0; r < 8; ++r) {
            ps[r] += __shfl_xor(ps[r], 16); ps[r] += __shfl_xor(ps[r], 32);
            pd[r] += __shfl_xor(pd[r], 16); pd[r] += __shfl_xor(pd[r], 32);
        }
        if (ATT == 4) {
            // wave wv == head wv; lanes 0..15 of each wave hold the head-sums for rows r0..r0+7
            if ((t & 48) == 0) {
#pragma unroll
                for (int r = 0; r < 8; ++r) {
                    int row = row0 + r0 + r;
                    if (row < nrows) { als[row * 4 + wv] = ps[r]; ald[row * 4 + wv] = pd[r]; }
                }
            }
        } else {
            __shared__ float redS[4][16][8];
            __shared__ float redD[4][16][8];
            if ((t & 48) == 0) {
#pragma unroll
                for (int r = 0; r < 8; ++r) { redS[wv][rg][r] = ps[r]; redD[wv][rg][r] = pd[r]; }
            }
            __syncthreads();
            if (t < 128) {
                int rg2 = t >> 3, r2 = t & 7;
                float s = redS[0][rg2][r2] + redS[1][rg2][r2] + redS[2][rg2][r2] + redS[3][rg2][r2];
                float d = redD[0][rg2][r2] + redD[1][rg2][r2] + redD[2][rg2][r2] + redD[3][rg2][r2];
                int row = row0 + rg2 * 8 + r2;
                if (row < nrows) { als[row] = s; ald[row] = d; }
            }
        }
    }
}

// ---------------------------------------------------------------- GAT aggregation: one wave per dst node, online softmax
template <int H>
__global__ __launch_bounds__(256) void k_agg(
    const int* __restrict__ rp, const int* __restrict__ col,
    const float* __restrict__ als, const float* __restrict__ ald_,
    const uint16_t* __restrict__ xs, const float* __restrict__ bias,
    const float* __restrict__ bg, const float* __restrict__ bb,
    const float* __restrict__ bm, const float* __restrict__ bv,
    float* __restrict__ h, int n)
{
    int node = blockIdx.x * 4 + (threadIdx.x >> 6);
    if (node >= n) return;
    int l = threadIdx.x & 63;
    int hl = (H == 4) ? (l >> 4) : 0;
    int c0 = l * 2;
    float ad = ald_[node * H + hl];
    float m = -INFINITY, z = 0.f, a0 = 0.f, a1 = 0.f;
    int jb = rp[node], je = rp[node + 1];
    int s = col[jb];
    for (int j = jb; j < je; ++j) {
        int sn = (j + 1 < je) ? col[j + 1] : 0;          // prefetch next col
        float lg = ((H == 4) ? als[s * 4 + hl] : als[s]) + ad;
        uint32_t xv = *(const uint32_t*)(xs + (size_t)s * 128 + c0);
        lg = lg > 0.f ? lg : 0.2f * lg;                  // leaky_relu 0.2
        float mn = fmaxf(m, lg);
        float sc = __expf(m - mn);
        float p  = __expf(lg - mn);
        float x0 = __uint_as_float(xv << 16);
        float x1 = __uint_as_float(xv & 0xffff0000u);
        z  = z * sc + p;
        a0 = a0 * sc + p * x0;
        a1 = a1 * sc + p * x1;
        m = mn;
        s = sn;
    }
    float inv = 1.f / (z + 1e-16f);
    float y0 = a0 * inv + bias[c0];
    float y1 = a1 * inv + bias[c0 + 1];
    y0 = (y0 - bm[c0])     * (bg[c0]     / sqrtf(bv[c0]     + 1e-5f)) + bb[c0];
    y1 = (y1 - bm[c0 + 1]) * (bg[c0 + 1] / sqrtf(bv[c0 + 1] + 1e-5f)) + bb[c0 + 1];
    y0 = y0 > 0.f ? y0 : expm1f(y0);             // ELU
    y1 = y1 > 0.f ? y1 : expm1f(y1);
    float2 hv = *(const float2*)&h[(size_t)node * 128 + c0];
    hv.x += y0; hv.y += y1;
    *(float2*)&h[(size_t)node * 128 + c0] = hv;  // residual, in-place (own row only)
}

// ---------------------------------------------------------------- readout
__global__ __launch_bounds__(256) void k_scores(
    const float* __restrict__ h, const float* __restrict__ w1, const float* __restrict__ b1,
    const float* __restrict__ w2, const float* __restrict__ b2,
    float* __restrict__ scores, int n)
{
    int node = blockIdx.x * 4 + (threadIdx.x >> 6);
    if (node >= n) return;
    int l = threadIdx.x & 63;
    const float* hr = &h[(size_t)node * 128];
    float acc = b1[l];
#pragma unroll 8
    for (int k = 0; k < 128; k += 4) {
        float4 hv = *(const float4*)&hr[k];      // wave-uniform broadcast
        acc += hv.x * w1[k * 64 + l] + hv.y * w1[(k + 1) * 64 + l]
             + hv.z * w1[(k + 2) * 64 + l] + hv.w * w1[(k + 3) * 64 + l];
    }
    float sc = tanhf(acc) * w2[l];
#pragma unroll
    for (int off = 32; off; off >>= 1) sc += __shfl_xor(sc, off);
    if (l == 0) scores[node] = sc + b2[0];
}
__global__ void k_graph_ptr(const int* __restrict__ batch, int* __restrict__ gptr, int n, int B) {
    int i = blockIdx.x * 256 + threadIdx.x;
    if (i >= n) return;
    int b = batch[i];
    int bp = (i == 0) ? -1 : batch[i - 1];
    for (int g = bp + 1; g <= b; ++g) gptr[g] = i;
    if (i == n - 1)
        for (int g = b + 1; g <= B; ++g) gptr[g] = n;
}
__global__ __launch_bounds__(256) void k_graph_mz(const int* __restrict__ gptr, const float* __restrict__ scores,
                                                  float* __restrict__ gmax, float* __restrict__ gz, int B) {
    int g = blockIdx.x * 4 + (threadIdx.x >> 6);
    if (g >= B) return;
    int l = threadIdx.x & 63;
    int s0 = gptr[g], s1 = gptr[g + 1];
    float m = -INFINITY;
    for (int i = s0 + l; i < s1; i += 64) m = fmaxf(m, scores[i]);
#pragma unroll
    for (int off = 32; off; off >>= 1) m = fmaxf(m, __shfl_xor(m, off));
    float z = 0.f;
    for (int i = s0 + l; i < s1; i += 64) z += __expf(scores[i] - m);
#pragma unroll
    for (int off = 32; off; off >>= 1) z += __shfl_xor(z, off);
    if (l == 0) { gmax[g] = m; gz[g] = z; }
}
__global__ void k_att(const int* __restrict__ batch, const float* __restrict__ scores,
                      const float* __restrict__ gmax, const float* __restrict__ gz,
                      float* __restrict__ att, int n) {
    int i = blockIdx.x * 256 + threadIdx.x;
    if (i >= n) return;
    int b = batch[i];
    att[i] = __expf(scores[i] - gmax[b]) / gz[b];
}
__global__ __launch_bounds__(256) void k_emb(const int* __restrict__ gptr, const float* __restrict__ att,
                                             const float* __restrict__ h, float* __restrict__ emb) {
    __shared__ float sd[8][128];
    int g = blockIdx.x, t = threadIdx.x;
    int c4 = (t & 31) * 4, p = t >> 5;               // 8 node-partitions x 32 channel-quads
    int s0 = gptr[g], s1 = gptr[g + 1];
    float4 acc = make_float4(0.f, 0.f, 0.f, 0.f);
    for (int i = s0 + p; i < s1; i += 8) {
        float a = att[i];
        float4 hv = *(const float4*)&h[(size_t)i * 128 + c4];
        acc.x += a * hv.x; acc.y += a * hv.y; acc.z += a * hv.z; acc.w += a * hv.w;
    }
    *(float4*)&sd[p][c4] = acc;
    __syncthreads();
    if (t < 128) {
        float s = 0.f;
#pragma unroll
        for (int q = 0; q < 8; ++q) s += sd[q][t];
        emb[g * 128 + t] = s;
    }
}

// ---------------------------------------------------------------- launch
extern "C" void kernel_launch(void* const* d_in, const int* in_sizes, int n_in,
                              void* d_out, int out_size, void* d_ws, size_t ws_size,
                              hipStream_t stream)
{
    const float* x            = (const float*)d_in[0];
    const int*   eidx         = (const int*)d_in[1];
    const int*   batch        = (const int*)d_in[2];
    const float* W_in         = (const float*)d_in[3];
    const float* b_in         = (const float*)d_in[4];
    const float* lin_w        = (const float*)d_in[5];
    const float* att_src      = (const float*)d_in[6];
    const float* att_dst      = (const float*)d_in[7];
    const float* conv_b       = (const float*)d_in[8];
    const float* lin_w_last   = (const float*)d_in[9];
    const float* att_src_last = (const float*)d_in[10];
    const float* att_dst_last = (const float*)d_in[11];
    const float* b_last       = (const float*)d_in[12];
    const float* bn_g         = (const float*)d_in[13];
    const float* bn_b         = (const float*)d_in[14];
    const float* bn_m         = (const float*)d_in[15];
    const float* bn_v         = (const float*)d_in[16];
    const float* ro_w1        = (const float*)d_in[17];
    const float* ro_b1        = (const float*)d_in[18];
    const float* ro_w2        = (const float*)d_in[19];
    const float* ro_b2        = (const float*)d_in[20];

    const int N = in_sizes[0] / 128;
    const int E = in_sizes[1] / 2;
    const int B = 512;
    const int* esrc = eidx;
    const int* edst = eidx + E;

    char* wsp = (char*)d_ws;
    size_t off = 0;
    auto alloc = [&](size_t bytes) -> void* {
        void* p = wsp + off;
        off += (bytes + 511) & ~(size_t)511;
        return p;
    };
    float*    h      = (float*)alloc((size_t)N * 128 * 4);
    uint16_t* xs     = (uint16_t*)alloc((size_t)N * 128 * 2);
    float*    als    = (float*)alloc((size_t)N * 4 * 4);
    float*    ald    = (float*)alloc((size_t)N * 4 * 4);
    float*    scores = (float*)alloc((size_t)N * 4);
    int*      rp     = (int*)alloc((size_t)(N + 1) * 4);
    int*      col    = (int*)alloc((size_t)(E + N) * 4);
    int*      fill   = (int*)alloc((size_t)N * 4);
    int*      bsum   = (int*)alloc(4096);
    int*      gptr   = (int*)alloc((size_t)(B + 1) * 4);
    float*    gmax   = (float*)alloc((size_t)B * 4);
    float*    gz     = (float*)alloc((size_t)B * 4);
    (void)ws_size; (void)n_in; (void)out_size;

    float* emb = (float*)d_out;
    float* att = (float*)d_out + (size_t)B * 128;

    const int nb = (N + 1023) / 1024;
    hipLaunchKernelGGL(k_fill_ones, dim3((N + 255) / 256), dim3(256), 0, stream, fill, N);
    hipLaunchKernelGGL(k_count, dim3((E + 255) / 256), dim3(256), 0, stream, edst, fill, E);
    hipLaunchKernelGGL(k_scan1, dim3(nb), dim3(256), 0, stream, fill, bsum, N);
    hipLaunchKernelGGL(k_scan2, dim3(1), dim3(128), 0, stream, bsum, nb);
    hipLaunchKernelGGL(k_scan3, dim3(nb), dim3(256), 0, stream, fill, bsum, rp, N, E + N);
    hipLaunchKernelGGL(k_zero_i, dim3((N + 255) / 256), dim3(256), 0, stream, fill, N);
    hipLaunchKernelGGL(k_scatter, dim3((E + N + 255) / 256), dim3(256), 0, stream, esrc, edst, rp, fill, col, E, N);

    const int ntiles = (N + 127) / 128;
    hipLaunchKernelGGL((k_gemm<0, 0>), dim3(ntiles), dim3(256), 0, stream,
                       x, W_in, b_in, (void*)h, (const float*)nullptr, (const float*)nullptr,
                       (float*)nullptr, (float*)nullptr, N);
    for (int i = 0; i < 2; ++i) {
        hipLaunchKernelGGL((k_gemm<4, 1>), dim3(ntiles), dim3(256), 0, stream,
                           h, lin_w + (size_t)i * 16384, (const float*)nullptr, (void*)xs,
                           att_src + i * 128, att_dst + i * 128, als, ald, N);
        hipLaunchKernelGGL((k_agg<4>), dim3((N + 3) / 4), dim3(256), 0, stream,
                           rp, col, als, ald, xs, conv_b + i * 128,
                           bn_g + i * 128, bn_b + i * 128, bn_m + i * 128, bn_v + i * 128, h, N);
    }
    hipLaunchKernelGGL((k_gemm<1, 1>), dim3(ntiles), dim3(256), 0, stream,
                       h, lin_w_last, (const float*)nullptr, (void*)xs,
                       att_src_last, att_dst_last, als, ald, N);
    hipLaunchKernelGGL((k_agg<1>), dim3((N + 3) / 4), dim3(256), 0, stream,
                       rp, col, als, ald, xs, b_last,
                       bn_g + 256, bn_b + 256, bn_m + 256, bn_v + 256, h, N);

    hipLaunchKernelGGL(k_scores, dim3((N + 3) / 4), dim3(256), 0, stream,
                       h, ro_w1, ro_b1, ro_w2, ro_b2, scores, N);
    hipLaunchKernelGGL(k_graph_ptr, dim3((N + 255) / 256), dim3(256), 0, stream, batch, gptr, N, B);
    hipLaunchKernelGGL(k_graph_mz, dim3((B + 3) / 4), dim3(256), 0, stream, gptr, scores, gmax, gz, B);
    hipLaunchKernelGGL(k_att, dim3((N + 255) / 256), dim3(256), 0, stream, batch, scores, gmax, gz, att, N);
    hipLaunchKernelGGL(k_emb, dim3(B), dim3(256), 0, stream, gptr, att, h, emb);
}

// Round 3
// 831.703 us; speedup vs baseline: 1.6255x; 1.5456x over previous
//
#include <hip/hip_runtime.h>
#include <math.h>
#include <stdint.h>

static __device__ __forceinline__ uint32_t f2bf(float x) {
    uint32_t u = __float_as_uint(x);
    return (u + 0x7fffu + ((u >> 16) & 1u)) >> 16;   // RNE
}
static __device__ __forceinline__ float bflo(uint32_t v) { return __uint_as_float(v << 16); }
static __device__ __forceinline__ float bfhi(uint32_t v) { return __uint_as_float(v & 0xffff0000u); }

// ---------------------------------------------------------------- CSR build (rows padded to multiple of 4)
__global__ void k_fill_ones(int* __restrict__ f, int n) {
    int i = blockIdx.x * 256 + threadIdx.x;
    if (i < n) f[i] = 1;
}
__global__ void k_count(const int* __restrict__ dst, int* __restrict__ f, int e) {
    int i = blockIdx.x * 256 + threadIdx.x;
    if (i < e) atomicAdd(&f[dst[i]], 1);
}
__global__ __launch_bounds__(256) void k_scan1(const int* __restrict__ cnt, int* __restrict__ bsum, int n) {
    __shared__ int sd[256];
    int base = blockIdx.x * 1024, t = threadIdx.x;
    int s = 0;
#pragma unroll
    for (int i = 0; i < 4; ++i) {
        int idx = base + t * 4 + i;
        if (idx < n) s += (cnt[idx] + 3) & ~3;       // pad4
    }
    sd[t] = s; __syncthreads();
    for (int o = 128; o; o >>= 1) {
        if (t < o) sd[t] += sd[t + o];
        __syncthreads();
    }
    if (t == 0) bsum[blockIdx.x] = sd[0];
}
__global__ void k_scan2(int* __restrict__ bsum, int nb) {
    __shared__ int sd[128];
    int t = threadIdx.x;
    int v = (t < nb) ? bsum[t] : 0;
    sd[t] = v; __syncthreads();
    for (int o = 1; o < 128; o <<= 1) {
        int u = (t >= o) ? sd[t - o] : 0;
        __syncthreads();
        sd[t] += u;
        __syncthreads();
    }
    if (t < nb) bsum[t] = sd[t] - v;  // exclusive
}
__global__ __launch_bounds__(256) void k_scan3(const int* __restrict__ cnt, const int* __restrict__ bsum,
                                               int* __restrict__ rp, int n) {
    __shared__ int sd[256];
    int base = blockIdx.x * 1024, t = threadIdx.x;
    int v[4]; int s = 0;
#pragma unroll
    for (int i = 0; i < 4; ++i) {
        int idx = base + t * 4 + i;
        v[i] = (idx < n) ? ((cnt[idx] + 3) & ~3) : 0;    // pad4
        s += v[i];
    }
    sd[t] = s; __syncthreads();
    for (int o = 1; o < 256; o <<= 1) {
        int u = (t >= o) ? sd[t - o] : 0;
        __syncthreads();
        sd[t] += u;
        __syncthreads();
    }
    int excl = sd[t] - s + bsum[blockIdx.x];
#pragma unroll
    for (int i = 0; i < 4; ++i) {
        int idx = base + t * 4 + i;
        if (idx < n) rp[idx] = excl;
        excl += v[i];
        if (idx == n - 1) rp[n] = excl;
    }
}
__global__ void k_zero_i(int* __restrict__ f, int n) {
    int i = blockIdx.x * 256 + threadIdx.x;
    if (i < n) f[i] = 0;
}
__global__ void k_fill_m1(int* __restrict__ f, int n) {
    int i = blockIdx.x * 256 + threadIdx.x;
    if (i < n) f[i] = -1;
}
__global__ void k_scatter(const int* __restrict__ src, const int* __restrict__ dst,
                          const int* __restrict__ rp, int* __restrict__ fill, int* __restrict__ col,
                          int e, int n) {
    int i = blockIdx.x * 256 + threadIdx.x;
    int tot = e + n;
    if (i >= tot) return;
    int s, d;
    if (i < e) { s = src[i]; d = dst[i]; }
    else       { s = d = i - e; }               // self loops
    int p = rp[d] + atomicAdd(&fill[d], 1);
    col[p] = s;
}
// fold bias + BN into scale/shift per channel (3 layers x 128 ch)
__global__ void k_bnprep(const float* __restrict__ conv_b, const float* __restrict__ b_last,
                         const float* __restrict__ bn_g, const float* __restrict__ bn_b,
                         const float* __restrict__ bn_m, const float* __restrict__ bn_v,
                         float* __restrict__ sc, float* __restrict__ sh) {
    int i = blockIdx.x * 128 + threadIdx.x;
    if (i >= 384) return;
    int layer = i >> 7, c = i & 127;
    float bias = (layer < 2) ? conv_b[layer * 128 + c] : b_last[c];
    float s = bn_g[i] * __frsqrt_rn(bn_v[i] + 1e-5f);
    sc[i] = s;
    sh[i] = (bias - bn_m[i]) * s + bn_b[i];
}

// ---------------------------------------------------------------- GEMM 128x128 tile, 8x8 micro-tile, persistent
template <int ATT, int OBF>
__global__ __launch_bounds__(256) void k_gemm(
    const float* __restrict__ A, const float* __restrict__ W,
    const float* __restrict__ bias, void* __restrict__ outv,
    const float* __restrict__ atts, const float* __restrict__ attd,
    float* __restrict__ als, float* __restrict__ ald,
    int nrows, int ntiles)
{
    __shared__ float Ws[128 * 128];   // 64 KB
    __shared__ float As[16][128];     // 8 KB
    const int t = threadIdx.x;
    {
        const float4* W4 = (const float4*)W;
        float4* S4 = (float4*)Ws;
#pragma unroll
        for (int i = 0; i < 16; ++i) S4[t + i * 256] = W4[t + i * 256];
    }
    const int rg = t & 15, cg = t >> 4;
    const int r0 = rg * 8, c0 = cg * 8;
    const int wv = t >> 6;
    // A-staging constants: thread loads (ar, ak0) and (ar, ak1)
    const int ar = (t * 2) >> 2;
    const int ak0 = ((t * 2) & 3) * 4, ak1 = ((t * 2 + 1) & 3) * 4;

    float bloc[8], avs[8], avd[8];
    if (ATT == 0) {
#pragma unroll
        for (int j = 0; j < 8; ++j) bloc[j] = bias[c0 + j];
    } else {
#pragma unroll
        for (int j = 0; j < 8; ++j) { avs[j] = atts[c0 + j]; avd[j] = attd[c0 + j]; }
    }

    for (int tile = blockIdx.x; tile < ntiles; tile += gridDim.x) {
        const int row0 = tile * 128;
        float4 v0 = make_float4(0.f, 0.f, 0.f, 0.f), v1 = v0;
        {
            int row = row0 + ar;
            if (row < nrows) {
                v0 = *(const float4*)&A[(size_t)row * 128 + ak0];
                v1 = *(const float4*)&A[(size_t)row * 128 + ak1];
            }
        }
        float acc[8][8] = {};
        for (int kc = 0; kc < 8; ++kc) {
            __syncthreads();
            As[ak0 + 0][ar] = v0.x; As[ak0 + 1][ar] = v0.y; As[ak0 + 2][ar] = v0.z; As[ak0 + 3][ar] = v0.w;
            As[ak1 + 0][ar] = v1.x; As[ak1 + 1][ar] = v1.y; As[ak1 + 2][ar] = v1.z; As[ak1 + 3][ar] = v1.w;
            __syncthreads();
            if (kc < 7) {
                int row = row0 + ar;
                v0 = make_float4(0.f, 0.f, 0.f, 0.f); v1 = v0;
                if (row < nrows) {
                    v0 = *(const float4*)&A[(size_t)row * 128 + (kc + 1) * 16 + ak0];
                    v1 = *(const float4*)&A[(size_t)row * 128 + (kc + 1) * 16 + ak1];
                }
            }
#pragma unroll
            for (int kk = 0; kk < 16; ++kk) {
                float a[8], w[8];
                *(float4*)&a[0] = *(const float4*)&As[kk][r0];
                *(float4*)&a[4] = *(const float4*)&As[kk][r0 + 4];
                *(float4*)&w[0] = *(const float4*)&Ws[(kc * 16 + kk) * 128 + c0];
                *(float4*)&w[4] = *(const float4*)&Ws[(kc * 16 + kk) * 128 + c0 + 4];
#pragma unroll
                for (int r = 0; r < 8; ++r)
#pragma unroll
                    for (int j = 0; j < 8; ++j)
                        acc[r][j] += a[r] * w[j];
            }
        }

        // ---- store
        if (OBF) {
            uint16_t* out = (uint16_t*)outv;
#pragma unroll
            for (int r = 0; r < 8; ++r) {
                int row = row0 + r0 + r;
                if (row < nrows) {
                    uint32_t up[4];
#pragma unroll
                    for (int jj = 0; jj < 4; ++jj)
                        up[jj] = (f2bf(acc[r][2 * jj + 1]) << 16) | f2bf(acc[r][2 * jj]);
                    *(uint4*)&out[(size_t)row * 128 + c0] = make_uint4(up[0], up[1], up[2], up[3]);
                }
            }
        } else {
            float* out = (float*)outv;
#pragma unroll
            for (int r = 0; r < 8; ++r) {
                int row = row0 + r0 + r;
                if (row < nrows) {
                    float o[8];
#pragma unroll
                    for (int j = 0; j < 8; ++j) o[j] = acc[r][j] + bloc[j];
                    *(float4*)&out[(size_t)row * 128 + c0]     = *(float4*)&o[0];
                    *(float4*)&out[(size_t)row * 128 + c0 + 4] = *(float4*)&o[4];
                }
            }
        }

        // ---- attention-logit epilogue
        if (ATT > 0) {
            float ps[8], pd[8];
#pragma unroll
            for (int r = 0; r < 8; ++r) {
                float s = 0.f, d = 0.f;
#pragma unroll
                for (int j = 0; j < 8; ++j) { s += acc[r][j] * avs[j]; d += acc[r][j] * avd[j]; }
                ps[r] = s; pd[r] = d;
            }
#pragma unroll
            for (int r = 0; r < 8; ++r) {
                ps[r] += __shfl_xor(ps[r], 16); ps[r] += __shfl_xor(ps[r], 32);
                pd[r] += __shfl_xor(pd[r], 16); pd[r] += __shfl_xor(pd[r], 32);
            }
            if (ATT == 4) {
                if ((t & 48) == 0) {
#pragma unroll
                    for (int r = 0; r < 8; ++r) {
                        int row = row0 + r0 + r;
                        if (row < nrows) { als[row * 4 + wv] = ps[r]; ald[row * 4 + wv] = pd[r]; }
                    }
                }
            } else {
                __shared__ float redS[4][16][8];
                __shared__ float redD[4][16][8];
                if ((t & 48) == 0) {
#pragma unroll
                    for (int r = 0; r < 8; ++r) { redS[wv][rg][r] = ps[r]; redD[wv][rg][r] = pd[r]; }
                }
                __syncthreads();
                if (t < 128) {
                    int rg2 = t >> 3, r2 = t & 7;
                    float s = redS[0][rg2][r2] + redS[1][rg2][r2] + redS[2][rg2][r2] + redS[3][rg2][r2];
                    float d = redD[0][rg2][r2] + redD[1][rg2][r2] + redD[2][rg2][r2] + redD[3][rg2][r2];
                    int row = row0 + rg2 * 8 + r2;
                    if (row < nrows) { als[row] = s; ald[row] = d; }
                }
                __syncthreads();
            }
        }
    }
}

// ---------------------------------------------------------------- GAT aggregation: one wave per dst, 4-edge groups
template <int H>
__global__ __launch_bounds__(256) void k_agg(
    const int* __restrict__ rp, const int* __restrict__ col,
    const float* __restrict__ als, const float* __restrict__ ald_,
    const uint16_t* __restrict__ xs, const float* __restrict__ bnsc,
    const float* __restrict__ bnsh, float* __restrict__ h, int n)
{
    int node = blockIdx.x * 4 + (threadIdx.x >> 6);
    if (node >= n) return;
    int l = threadIdx.x & 63;
    int hl = (H == 4) ? (l >> 4) : 0;
    int c0 = l * 2;
    float ad = ald_[node * H + hl];
    int jb = rp[node], je = rp[node + 1];
    float2 hv = *(const float2*)&h[(size_t)node * 128 + c0];       // residual, prefetch
    float sc0v = bnsc[c0], sc1v = bnsc[c0 + 1];
    float sh0v = bnsh[c0], sh1v = bnsh[c0 + 1];

    float m = -INFINITY, z = 0.f, a0 = 0.f, a1 = 0.f;
    for (int j = jb; j < je; j += 4) {                              // je-jb multiple of 4
        int s0 = col[j], s1 = col[j + 1], s2 = col[j + 2], s3 = col[j + 3];
        int t0 = s0 < 0 ? 0 : s0, t1 = s1 < 0 ? 0 : s1, t2 = s2 < 0 ? 0 : s2, t3 = s3 < 0 ? 0 : s3;
        // issue all 8 gathers up front (independent)
        float l0 = (H == 4) ? als[t0 * 4 + hl] : als[t0];
        float l1 = (H == 4) ? als[t1 * 4 + hl] : als[t1];
        float l2 = (H == 4) ? als[t2 * 4 + hl] : als[t2];
        float l3 = (H == 4) ? als[t3 * 4 + hl] : als[t3];
        uint32_t x0 = *(const uint32_t*)(xs + (size_t)t0 * 128 + c0);
        uint32_t x1 = *(const uint32_t*)(xs + (size_t)t1 * 128 + c0);
        uint32_t x2 = *(const uint32_t*)(xs + (size_t)t2 * 128 + c0);
        uint32_t x3 = *(const uint32_t*)(xs + (size_t)t3 * 128 + c0);
        l0 += ad; l1 += ad; l2 += ad; l3 += ad;
        l0 = l0 > 0.f ? l0 : 0.2f * l0;  l1 = l1 > 0.f ? l1 : 0.2f * l1;
        l2 = l2 > 0.f ? l2 : 0.2f * l2;  l3 = l3 > 0.f ? l3 : 0.2f * l3;
        l0 = s0 < 0 ? -1e30f : l0;  l1 = s1 < 0 ? -1e30f : l1;
        l2 = s2 < 0 ? -1e30f : l2;  l3 = s3 < 0 ? -1e30f : l3;
        float gm = fmaxf(fmaxf(l0, l1), fmaxf(l2, l3));
        float mn = fmaxf(m, gm);
        float sc = __expf(m - mn);
        float p0 = __expf(l0 - mn), p1 = __expf(l1 - mn), p2 = __expf(l2 - mn), p3 = __expf(l3 - mn);
        z  = fmaf(z,  sc, (p0 + p1) + (p2 + p3));
        a0 = fmaf(a0, sc, fmaf(p0, bflo(x0), fmaf(p1, bflo(x1), fmaf(p2, bflo(x2), p3 * bflo(x3)))));
        a1 = fmaf(a1, sc, fmaf(p0, bfhi(x0), fmaf(p1, bfhi(x1), fmaf(p2, bfhi(x2), p3 * bfhi(x3)))));
        m = mn;
    }
    float inv = 1.f / (z + 1e-16f);
    float y0 = fmaf(a0 * inv, sc0v, sh0v);
    float y1 = fmaf(a1 * inv, sc1v, sh1v);
    y0 = y0 > 0.f ? y0 : expm1f(y0);             // ELU
    y1 = y1 > 0.f ? y1 : expm1f(y1);
    hv.x += y0; hv.y += y1;
    *(float2*)&h[(size_t)node * 128 + c0] = hv;  // residual, in-place (own row only)
}

// ---------------------------------------------------------------- readout scores: tiled GEMV batch
__global__ __launch_bounds__(256) void k_scores(
    const float* __restrict__ h, const float* __restrict__ w1, const float* __restrict__ b1,
    const float* __restrict__ w2, const float* __restrict__ b2,
    float* __restrict__ scores, int n)
{
    __shared__ float W1s[128 * 64];     // 32 KB
    __shared__ float As[16][128];       // 8 KB
    __shared__ float red[4][32][4];     // 2 KB
    const int t = threadIdx.x;
    {
        const float4* w4 = (const float4*)w1;
        float4* s4 = (float4*)W1s;
#pragma unroll
        for (int i = 0; i < 8; ++i) s4[t + i * 256] = w4[t + i * 256];
    }
    const int rg = t & 31, cg = t >> 5;     // 32 row-groups x 8 col-groups
    const int r0 = rg * 4, c0 = cg * 8;
    const int row0 = blockIdx.x * 128;
    const int ar = (t * 2) >> 2;
    const int ak0 = ((t * 2) & 3) * 4, ak1 = ((t * 2 + 1) & 3) * 4;
    float bloc[8], w2loc[8];
#pragma unroll
    for (int j = 0; j < 8; ++j) { bloc[j] = b1[c0 + j]; w2loc[j] = w2[c0 + j]; }

    float acc[4][8] = {};
    for (int kc = 0; kc < 8; ++kc) {
        __syncthreads();
        {
            float4 v0 = make_float4(0.f, 0.f, 0.f, 0.f), v1 = v0;
            int row = row0 + ar;
            if (row < n) {
                v0 = *(const float4*)&h[(size_t)row * 128 + kc * 16 + ak0];
                v1 = *(const float4*)&h[(size_t)row * 128 + kc * 16 + ak1];
            }
            As[ak0 + 0][ar] = v0.x; As[ak0 + 1][ar] = v0.y; As[ak0 + 2][ar] = v0.z; As[ak0 + 3][ar] = v0.w;
            As[ak1 + 0][ar] = v1.x; As[ak1 + 1][ar] = v1.y; As[ak1 + 2][ar] = v1.z; As[ak1 + 3][ar] = v1.w;
        }
        __syncthreads();
#pragma unroll
        for (int kk = 0; kk < 16; ++kk) {
            float a[4], w[8];
            *(float4*)&a[0] = *(const float4*)&As[kk][r0];
            *(float4*)&w[0] = *(const float4*)&W1s[(kc * 16 + kk) * 64 + c0];
            *(float4*)&w[4] = *(const float4*)&W1s[(kc * 16 + kk) * 64 + c0 + 4];
#pragma unroll
            for (int r = 0; r < 4; ++r)
#pragma unroll
                for (int j = 0; j < 8; ++j) acc[r][j] += a[r] * w[j];
        }
    }
    float part[4];
#pragma unroll
    for (int r = 0; r < 4; ++r) {
        float s = 0.f;
#pragma unroll
        for (int j = 0; j < 8; ++j) s += tanhf(acc[r][j] + bloc[j]) * w2loc[j];
        part[r] = s;
    }
#pragma unroll
    for (int r = 0; r < 4; ++r) part[r] += __shfl_xor(part[r], 32);
    const int wv = t >> 6;
    if ((t & 32) == 0) {
#pragma unroll
        for (int r = 0; r < 4; ++r) red[wv][rg][r] = part[r];
    }
    __syncthreads();
    if (t < 128) {
        int row = row0 + t;
        if (row < n) {
            float s = red[0][t >> 2][t & 3] + red[1][t >> 2][t & 3]
                    + red[2][t >> 2][t & 3] + red[3][t >> 2][t & 3];
            scores[row] = s + b2[0];
        }
    }
}
__global__ void k_graph_ptr(const int* __restrict__ batch, int* __restrict__ gptr, int n, int B) {
    int i = blockIdx.x * 256 + threadIdx.x;
    if (i >= n) return;
    int b = batch[i];
    int bp = (i == 0) ? -1 : batch[i - 1];
    for (int g = bp + 1; g <= b; ++g) gptr[g] = i;
    if (i == n - 1)
        for (int g = b + 1; g <= B; ++g) gptr[g] = n;
}
__global__ __launch_bounds__(256) void k_graph_mz(const int* __restrict__ gptr, const float* __restrict__ scores,
                                                  float* __restrict__ gmax, float* __restrict__ gz, int B) {
    int g = blockIdx.x * 4 + (threadIdx.x >> 6);
    if (g >= B) return;
    int l = threadIdx.x & 63;
    int s0 = gptr[g], s1 = gptr[g + 1];
    float m = -INFINITY;
    for (int i = s0 + l; i < s1; i += 64) m = fmaxf(m, scores[i]);
#pragma unroll
    for (int off = 32; off; off >>= 1) m = fmaxf(m, __shfl_xor(m, off));
    float z = 0.f;
    for (int i = s0 + l; i < s1; i += 64) z += __expf(scores[i] - m);
#pragma unroll
    for (int off = 32; off; off >>= 1) z += __shfl_xor(z, off);
    if (l == 0) { gmax[g] = m; gz[g] = z; }
}
__global__ void k_att(const int* __restrict__ batch, const float* __restrict__ scores,
                      const float* __restrict__ gmax, const float* __restrict__ gz,
                      float* __restrict__ att, int n) {
    int i = blockIdx.x * 256 + threadIdx.x;
    if (i >= n) return;
    int b = batch[i];
    att[i] = __expf(scores[i] - gmax[b]) / gz[b];
}
__global__ __launch_bounds__(256) void k_emb(const int* __restrict__ gptr, const float* __restrict__ att,
                                             const float* __restrict__ h, float* __restrict__ emb) {
    __shared__ float sd[16][64];
    int g = blockIdx.x >> 1, half = blockIdx.x & 1;
    int t = threadIdx.x;
    int cq = (t & 15) * 4;
    int c = half * 64 + cq;
    int p = t >> 4;                                  // 16 node-partitions
    int s0 = gptr[g], s1 = gptr[g + 1];
    float4 acc = make_float4(0.f, 0.f, 0.f, 0.f);
    for (int i = s0 + p; i < s1; i += 16) {
        float a = att[i];
        float4 hvv = *(const float4*)&h[(size_t)i * 128 + c];
        acc.x += a * hvv.x; acc.y += a * hvv.y; acc.z += a * hvv.z; acc.w += a * hvv.w;
    }
    *(float4*)&sd[p][cq] = acc;
    __syncthreads();
    if (t < 64) {
        float s = 0.f;
#pragma unroll
        for (int q = 0; q < 16; ++q) s += sd[q][t];
        emb[g * 128 + half * 64 + t] = s;
    }
}

// ---------------------------------------------------------------- launch
extern "C" void kernel_launch(void* const* d_in, const int* in_sizes, int n_in,
                              void* d_out, int out_size, void* d_ws, size_t ws_size,
                              hipStream_t stream)
{
    const float* x            = (const float*)d_in[0];
    const int*   eidx         = (const int*)d_in[1];
    const int*   batch        = (const int*)d_in[2];
    const float* W_in         = (const float*)d_in[3];
    const float* b_in         = (const float*)d_in[4];
    const float* lin_w        = (const float*)d_in[5];
    const float* att_src      = (const float*)d_in[6];
    const float* att_dst      = (const float*)d_in[7];
    const float* conv_b       = (const float*)d_in[8];
    const float* lin_w_last   = (const float*)d_in[9];
    const float* att_src_last = (const float*)d_in[10];
    const float* att_dst_last = (const float*)d_in[11];
    const float* b_last       = (const float*)d_in[12];
    const float* bn_g         = (const float*)d_in[13];
    const float* bn_b         = (const float*)d_in[14];
    const float* bn_m         = (const float*)d_in[15];
    const float* bn_v         = (const float*)d_in[16];
    const float* ro_w1        = (const float*)d_in[17];
    const float* ro_b1        = (const float*)d_in[18];
    const float* ro_w2        = (const float*)d_in[19];
    const float* ro_b2        = (const float*)d_in[20];

    const int N = in_sizes[0] / 128;
    const int E = in_sizes[1] / 2;
    const int B = 512;
    const int* esrc = eidx;
    const int* edst = eidx + E;
    const int colcap = E + 4 * N;                    // padded upper bound

    char* wsp = (char*)d_ws;
    size_t off = 0;
    auto alloc = [&](size_t bytes) -> void* {
        void* p = wsp + off;
        off += (bytes + 511) & ~(size_t)511;
        return p;
    };
    float*    h      = (float*)alloc((size_t)N * 128 * 4);
    uint16_t* xs     = (uint16_t*)alloc((size_t)N * 128 * 2);
    float*    als    = (float*)alloc((size_t)N * 4 * 4);
    float*    ald    = (float*)alloc((size_t)N * 4 * 4);
    float*    scores = (float*)alloc((size_t)N * 4);
    int*      rp     = (int*)alloc((size_t)(N + 1) * 4);
    int*      col    = (int*)alloc((size_t)colcap * 4);
    int*      fill   = (int*)alloc((size_t)N * 4);
    int*      bsum   = (int*)alloc(4096);
    int*      gptr   = (int*)alloc((size_t)(B + 1) * 4);
    float*    gmax   = (float*)alloc((size_t)B * 4);
    float*    gz     = (float*)alloc((size_t)B * 4);
    float*    bnsc   = (float*)alloc(384 * 4);
    float*    bnsh   = (float*)alloc(384 * 4);
    (void)ws_size; (void)n_in; (void)out_size;

    float* emb = (float*)d_out;
    float* att = (float*)d_out + (size_t)B * 128;

    const int nb = (N + 1023) / 1024;
    hipLaunchKernelGGL(k_fill_ones, dim3((N + 255) / 256), dim3(256), 0, stream, fill, N);
    hipLaunchKernelGGL(k_count, dim3((E + 255) / 256), dim3(256), 0, stream, edst, fill, E);
    hipLaunchKernelGGL(k_scan1, dim3(nb), dim3(256), 0, stream, fill, bsum, N);
    hipLaunchKernelGGL(k_scan2, dim3(1), dim3(128), 0, stream, bsum, nb);
    hipLaunchKernelGGL(k_scan3, dim3(nb), dim3(256), 0, stream, fill, bsum, rp, N);
    hipLaunchKernelGGL(k_zero_i, dim3((N + 255) / 256), dim3(256), 0, stream, fill, N);
    hipLaunchKernelGGL(k_fill_m1, dim3((colcap + 255) / 256), dim3(256), 0, stream, col, colcap);
    hipLaunchKernelGGL(k_scatter, dim3((E + N + 255) / 256), dim3(256), 0, stream, esrc, edst, rp, fill, col, E, N);
    hipLaunchKernelGGL(k_bnprep, dim3(3), dim3(128), 0, stream, conv_b, b_last, bn_g, bn_b, bn_m, bn_v, bnsc, bnsh);

    const int ntiles = (N + 127) / 128;
    hipLaunchKernelGGL((k_gemm<0, 0>), dim3(512), dim3(256), 0, stream,
                       x, W_in, b_in, (void*)h, (const float*)nullptr, (const float*)nullptr,
                       (float*)nullptr, (float*)nullptr, N, ntiles);
    for (int i = 0; i < 2; ++i) {
        hipLaunchKernelGGL((k_gemm<4, 1>), dim3(512), dim3(256), 0, stream,
                           h, lin_w + (size_t)i * 16384, (const float*)nullptr, (void*)xs,
                           att_src + i * 128, att_dst + i * 128, als, ald, N, ntiles);
        hipLaunchKernelGGL((k_agg<4>), dim3((N + 3) / 4), dim3(256), 0, stream,
                           rp, col, als, ald, xs, bnsc + i * 128, bnsh + i * 128, h, N);
    }
    hipLaunchKernelGGL((k_gemm<1, 1>), dim3(512), dim3(256), 0, stream,
                       h, lin_w_last, (const float*)nullptr, (void*)xs,
                       att_src_last, att_dst_last, als, ald, N, ntiles);
    hipLaunchKernelGGL((k_agg<1>), dim3((N + 3) / 4), dim3(256), 0, stream,
                       rp, col, als, ald, xs, bnsc + 256, bnsh + 256, h, N);

    hipLaunchKernelGGL(k_scores, dim3(ntiles), dim3(256), 0, stream,
                       h, ro_w1, ro_b1, ro_w2, ro_b2, scores, N);
    hipLaunchKernelGGL(k_graph_ptr, dim3((N + 255) / 256), dim3(256), 0, stream, batch, gptr, N, B);
    hipLaunchKernelGGL(k_graph_mz, dim3((B + 3) / 4), dim3(256), 0, stream, gptr, scores, gmax, gz, B);
    hipLaunchKernelGGL(k_att, dim3((N + 255) / 256), dim3(256), 0, stream, batch, scores, gmax, gz, att, N);
    hipLaunchKernelGGL(k_emb, dim3(B * 2), dim3(256), 0, stream, gptr, att, h, emb);
}

// Round 4
// 687.055 us; speedup vs baseline: 1.9678x; 1.2105x over previous
//
#include <hip/hip_runtime.h>
#include <math.h>
#include <stdint.h>

#define BSZ 512
#define BSH 9
#define NBKT_MAX 256

static __device__ __forceinline__ uint32_t f2bf(float x) {
    uint32_t u = __float_as_uint(x);
    return (u + 0x7fffu + ((u >> 16) & 1u)) >> 16;   // RNE
}
static __device__ __forceinline__ float bflo(uint32_t v) { return __uint_as_float(v << 16); }
static __device__ __forceinline__ float bfhi(uint32_t v) { return __uint_as_float(v & 0xffff0000u); }

// ---------------------------------------------------------------- bucketed CSR build
__global__ void k_binit(int* __restrict__ bcur, int nbkt, int cap) {
    int t = threadIdx.x;
    if (t < nbkt) bcur[t] = t * cap;
}
// Phase A: bin edges into dst-range buckets; contiguous chunk per block-bucket.
__global__ __launch_bounds__(256) void k_bucket(const int* __restrict__ src, const int* __restrict__ dst,
                                                int* __restrict__ bcur, uint32_t* __restrict__ bucketed,
                                                int e, int cap) {
    __shared__ int hist[NBKT_MAX];
    __shared__ int cur[NBKT_MAX];
    int t = threadIdx.x;
    hist[t] = 0;
    __syncthreads();
    int base = blockIdx.x * 8192;
#pragma unroll 4
    for (int i = 0; i < 32; ++i) {
        int ei = base + i * 256 + t;
        if (ei < e) atomicAdd(&hist[dst[ei] >> BSH], 1);
    }
    __syncthreads();
    int hc = hist[t];
    cur[t] = (hc > 0) ? atomicAdd(&bcur[t], hc) : 0;
    __syncthreads();
#pragma unroll 4
    for (int i = 0; i < 32; ++i) {
        int ei = base + i * 256 + t;
        if (ei < e) {
            int d = dst[ei], s = src[ei];
            int b = d >> BSH;
            int p = atomicAdd(&cur[b], 1);
            if (p < (b + 1) * cap)
                bucketed[p] = ((uint32_t)(d & (BSZ - 1)) << 23) | (uint32_t)s;
        }
    }
}
// Phase B1: per-bucket degree count (LDS atomics only)
__global__ __launch_bounds__(256) void k_bcount(const int* __restrict__ bcur, const uint32_t* __restrict__ bucketed,
                                                int* __restrict__ cnt, int n, int cap) {
    __shared__ int lf[BSZ];
    int b = blockIdx.x, t = threadIdx.x;
    int n0 = b << BSH;
    int nn = min(BSZ, n - n0);
    for (int i = t; i < nn; i += 256) lf[i] = 0;
    __syncthreads();
    int cb = min(bcur[b] - b * cap, cap);
    const uint32_t* ba = bucketed + (size_t)b * cap;
    for (int i = t; i < cb; i += 256) atomicAdd(&lf[ba[i] >> 23], 1);
    __syncthreads();
    for (int i = t; i < nn; i += 256) cnt[n0 + i] = lf[i] + 1;    // + self loop
}
__global__ __launch_bounds__(256) void k_scan1(const int* __restrict__ cnt, int* __restrict__ bsum, int n) {
    __shared__ int sd[256];
    int base = blockIdx.x * 1024, t = threadIdx.x;
    int s = 0;
#pragma unroll
    for (int i = 0; i < 4; ++i) {
        int idx = base + t * 4 + i;
        if (idx < n) s += (cnt[idx] + 3) & ~3;       // pad4
    }
    sd[t] = s; __syncthreads();
    for (int o = 128; o; o >>= 1) {
        if (t < o) sd[t] += sd[t + o];
        __syncthreads();
    }
    if (t == 0) bsum[blockIdx.x] = sd[0];
}
__global__ void k_scan2(int* __restrict__ bsum, int nb) {
    __shared__ int sd[128];
    int t = threadIdx.x;
    int v = (t < nb) ? bsum[t] : 0;
    sd[t] = v; __syncthreads();
    for (int o = 1; o < 128; o <<= 1) {
        int u = (t >= o) ? sd[t - o] : 0;
        __syncthreads();
        sd[t] += u;
        __syncthreads();
    }
    if (t < nb) bsum[t] = sd[t] - v;  // exclusive
}
__global__ __launch_bounds__(256) void k_scan3(const int* __restrict__ cnt, const int* __restrict__ bsum,
                                               int* __restrict__ rp, int n) {
    __shared__ int sd[256];
    int base = blockIdx.x * 1024, t = threadIdx.x;
    int v[4]; int s = 0;
#pragma unroll
    for (int i = 0; i < 4; ++i) {
        int idx = base + t * 4 + i;
        v[i] = (idx < n) ? ((cnt[idx] + 3) & ~3) : 0;    // pad4
        s += v[i];
    }
    sd[t] = s; __syncthreads();
    for (int o = 1; o < 256; o <<= 1) {
        int u = (t >= o) ? sd[t - o] : 0;
        __syncthreads();
        sd[t] += u;
        __syncthreads();
    }
    int excl = sd[t] - s + bsum[blockIdx.x];
#pragma unroll
    for (int i = 0; i < 4; ++i) {
        int idx = base + t * 4 + i;
        if (idx < n) rp[idx] = excl;
        excl += v[i];
        if (idx == n - 1) rp[n] = excl;
    }
}
// Phase B2: scatter bucket edges into this bucket's private col region; self-loops + pads
__global__ __launch_bounds__(256) void k_bscatter(const int* __restrict__ bcur, const uint32_t* __restrict__ bucketed,
                                                  const int* __restrict__ rp, int* __restrict__ col,
                                                  int n, int cap) {
    __shared__ int lf[BSZ];
    __shared__ int rpl[BSZ];
    int b = blockIdx.x, t = threadIdx.x;
    int n0 = b << BSH;
    int nn = min(BSZ, n - n0);
    for (int i = t; i < nn; i += 256) {
        int r = rp[n0 + i];
        rpl[i] = r;
        lf[i] = 1;
        col[r] = n0 + i;                              // self loop at slot 0
    }
    __syncthreads();
    int cb = min(bcur[b] - b * cap, cap);
    const uint32_t* ba = bucketed + (size_t)b * cap;
    for (int i = t; i < cb; i += 256) {
        uint32_t v = ba[i];
        int ld = (int)(v >> 23), s = (int)(v & 0x7fffffu);
        int o = atomicAdd(&lf[ld], 1);
        col[rpl[ld] + o] = s;
    }
    __syncthreads();
    for (int i = t; i < nn; i += 256) {
        int c = lf[i], end = (c + 3) & ~3;
        int r = rpl[i];
        for (int j = c; j < end; ++j) col[r + j] = -1;
    }
}
// fold bias + BN into scale/shift per channel (3 layers x 128 ch)
__global__ void k_bnprep(const float* __restrict__ conv_b, const float* __restrict__ b_last,
                         const float* __restrict__ bn_g, const float* __restrict__ bn_b,
                         const float* __restrict__ bn_m, const float* __restrict__ bn_v,
                         float* __restrict__ sc, float* __restrict__ sh) {
    int i = blockIdx.x * 128 + threadIdx.x;
    if (i >= 384) return;
    int layer = i >> 7, c = i & 127;
    float bias = (layer < 2) ? conv_b[layer * 128 + c] : b_last[c];
    float s = bn_g[i] * __frsqrt_rn(bn_v[i] + 1e-5f);
    sc[i] = s;
    sh[i] = (bias - bn_m[i]) * s + bn_b[i];
}

// ---------------------------------------------------------------- GEMM 128x128 tile, 8x8 micro-tile, persistent
template <int ATT, int OBF>
__global__ __launch_bounds__(256) void k_gemm(
    const float* __restrict__ A, const float* __restrict__ W,
    const float* __restrict__ bias, void* __restrict__ outv,
    const float* __restrict__ atts, const float* __restrict__ attd,
    float* __restrict__ als, float* __restrict__ ald,
    int nrows, int ntiles)
{
    __shared__ float Ws[128 * 128];   // 64 KB (reads are 16-lane broadcasts: conflict-free)
    __shared__ float As[16][132];     // padded stride 132: As reads <=2-way (free)
    const int t = threadIdx.x;
    {
        const float4* W4 = (const float4*)W;
        float4* S4 = (float4*)Ws;
#pragma unroll
        for (int i = 0; i < 16; ++i) S4[t + i * 256] = W4[t + i * 256];
    }
    const int rg = t & 15, cg = t >> 4;
    const int r0 = rg * 8, c0 = cg * 8;
    const int wv = t >> 6;
    const int ar = (t * 2) >> 2;
    const int ak0 = ((t * 2) & 3) * 4, ak1 = ((t * 2 + 1) & 3) * 4;

    float bloc[8], avs[8], avd[8];
    if (ATT == 0) {
#pragma unroll
        for (int j = 0; j < 8; ++j) bloc[j] = bias[c0 + j];
    } else {
#pragma unroll
        for (int j = 0; j < 8; ++j) { avs[j] = atts[c0 + j]; avd[j] = attd[c0 + j]; }
    }

    for (int tile = blockIdx.x; tile < ntiles; tile += gridDim.x) {
        const int row0 = tile * 128;
        float4 v0 = make_float4(0.f, 0.f, 0.f, 0.f), v1 = v0;
        {
            int row = row0 + ar;
            if (row < nrows) {
                v0 = *(const float4*)&A[(size_t)row * 128 + ak0];
                v1 = *(const float4*)&A[(size_t)row * 128 + ak1];
            }
        }
        float acc[8][8] = {};
        for (int kc = 0; kc < 8; ++kc) {
            __syncthreads();
            As[ak0 + 0][ar] = v0.x; As[ak0 + 1][ar] = v0.y; As[ak0 + 2][ar] = v0.z; As[ak0 + 3][ar] = v0.w;
            As[ak1 + 0][ar] = v1.x; As[ak1 + 1][ar] = v1.y; As[ak1 + 2][ar] = v1.z; As[ak1 + 3][ar] = v1.w;
            __syncthreads();
            if (kc < 7) {
                int row = row0 + ar;
                v0 = make_float4(0.f, 0.f, 0.f, 0.f); v1 = v0;
                if (row < nrows) {
                    v0 = *(const float4*)&A[(size_t)row * 128 + (kc + 1) * 16 + ak0];
                    v1 = *(const float4*)&A[(size_t)row * 128 + (kc + 1) * 16 + ak1];
                }
            }
#pragma unroll
            for (int kk = 0; kk < 16; ++kk) {
                float a[8], w[8];
                *(float4*)&a[0] = *(const float4*)&As[kk][r0];
                *(float4*)&a[4] = *(const float4*)&As[kk][r0 + 4];
                *(float4*)&w[0] = *(const float4*)&Ws[(kc * 16 + kk) * 128 + c0];
                *(float4*)&w[4] = *(const float4*)&Ws[(kc * 16 + kk) * 128 + c0 + 4];
#pragma unroll
                for (int r = 0; r < 8; ++r)
#pragma unroll
                    for (int j = 0; j < 8; ++j)
                        acc[r][j] += a[r] * w[j];
            }
        }

        // ---- store
        if (OBF) {
            uint16_t* out = (uint16_t*)outv;
#pragma unroll
            for (int r = 0; r < 8; ++r) {
                int row = row0 + r0 + r;
                if (row < nrows) {
                    uint32_t up[4];
#pragma unroll
                    for (int jj = 0; jj < 4; ++jj)
                        up[jj] = (f2bf(acc[r][2 * jj + 1]) << 16) | f2bf(acc[r][2 * jj]);
                    *(uint4*)&out[(size_t)row * 128 + c0] = make_uint4(up[0], up[1], up[2], up[3]);
                }
            }
        } else {
            float* out = (float*)outv;
#pragma unroll
            for (int r = 0; r < 8; ++r) {
                int row = row0 + r0 + r;
                if (row < nrows) {
                    float o[8];
#pragma unroll
                    for (int j = 0; j < 8; ++j) o[j] = acc[r][j] + bloc[j];
                    *(float4*)&out[(size_t)row * 128 + c0]     = *(float4*)&o[0];
                    *(float4*)&out[(size_t)row * 128 + c0 + 4] = *(float4*)&o[4];
                }
            }
        }

        // ---- attention-logit epilogue
        if (ATT > 0) {
            float ps[8], pd[8];
#pragma unroll
            for (int r = 0; r < 8; ++r) {
                float s = 0.f, d = 0.f;
#pragma unroll
                for (int j = 0; j < 8; ++j) { s += acc[r][j] * avs[j]; d += acc[r][j] * avd[j]; }
                ps[r] = s; pd[r] = d;
            }
#pragma unroll
            for (int r = 0; r < 8; ++r) {
                ps[r] += __shfl_xor(ps[r], 16); ps[r] += __shfl_xor(ps[r], 32);
                pd[r] += __shfl_xor(pd[r], 16); pd[r] += __shfl_xor(pd[r], 32);
            }
            if (ATT == 4) {
                if ((t & 48) == 0) {
#pragma unroll
                    for (int r = 0; r < 8; ++r) {
                        int row = row0 + r0 + r;
                        if (row < nrows) { als[row * 4 + wv] = ps[r]; ald[row * 4 + wv] = pd[r]; }
                    }
                }
            } else {
                __shared__ float redS[4][16][8];
                __shared__ float redD[4][16][8];
                if ((t & 48) == 0) {
#pragma unroll
                    for (int r = 0; r < 8; ++r) { redS[wv][rg][r] = ps[r]; redD[wv][rg][r] = pd[r]; }
                }
                __syncthreads();
                if (t < 128) {
                    int rg2 = t >> 3, r2 = t & 7;
                    float s = redS[0][rg2][r2] + redS[1][rg2][r2] + redS[2][rg2][r2] + redS[3][rg2][r2];
                    float d = redD[0][rg2][r2] + redD[1][rg2][r2] + redD[2][rg2][r2] + redD[3][rg2][r2];
                    int row = row0 + rg2 * 8 + r2;
                    if (row < nrows) { als[row] = s; ald[row] = d; }
                }
                __syncthreads();
            }
        }
    }
}

// ---------------------------------------------------------------- GAT aggregation: one wave per dst, 8-edge groups
template <int H>
__global__ __launch_bounds__(256) void k_agg(
    const int* __restrict__ rp, const int* __restrict__ col,
    const float* __restrict__ als, const float* __restrict__ ald_,
    const uint16_t* __restrict__ xs, const float* __restrict__ bnsc,
    const float* __restrict__ bnsh, float* __restrict__ h, int n)
{
    int node = blockIdx.x * 4 + (threadIdx.x >> 6);
    if (node >= n) return;
    int l = threadIdx.x & 63;
    int hl = (H == 4) ? (l >> 4) : 0;
    int c0 = l * 2;
    float ad = ald_[node * H + hl];
    int jb = rp[node], je = rp[node + 1];
    float2 hv = *(const float2*)&h[(size_t)node * 128 + c0];       // residual, prefetch
    float sc0v = bnsc[c0], sc1v = bnsc[c0 + 1];
    float sh0v = bnsh[c0], sh1v = bnsh[c0 + 1];

    float m = -INFINITY, z = 0.f, a0 = 0.f, a1 = 0.f;
    int j = jb;
    for (; j + 8 <= je; j += 8) {
        int4 ca = *(const int4*)&col[j];
        int4 cb = *(const int4*)&col[j + 4];
        int t0 = max(ca.x, 0), t1 = max(ca.y, 0), t2 = max(ca.z, 0), t3 = max(ca.w, 0);
        int t4 = max(cb.x, 0), t5 = max(cb.y, 0), t6 = max(cb.z, 0), t7 = max(cb.w, 0);
        float l0 = (H == 4) ? als[t0 * 4 + hl] : als[t0];
        float l1 = (H == 4) ? als[t1 * 4 + hl] : als[t1];
        float l2 = (H == 4) ? als[t2 * 4 + hl] : als[t2];
        float l3 = (H == 4) ? als[t3 * 4 + hl] : als[t3];
        float l4 = (H == 4) ? als[t4 * 4 + hl] : als[t4];
        float l5 = (H == 4) ? als[t5 * 4 + hl] : als[t5];
        float l6 = (H == 4) ? als[t6 * 4 + hl] : als[t6];
        float l7 = (H == 4) ? als[t7 * 4 + hl] : als[t7];
        uint32_t x0 = *(const uint32_t*)(xs + (size_t)t0 * 128 + c0);
        uint32_t x1 = *(const uint32_t*)(xs + (size_t)t1 * 128 + c0);
        uint32_t x2 = *(const uint32_t*)(xs + (size_t)t2 * 128 + c0);
        uint32_t x3 = *(const uint32_t*)(xs + (size_t)t3 * 128 + c0);
        uint32_t x4 = *(const uint32_t*)(xs + (size_t)t4 * 128 + c0);
        uint32_t x5 = *(const uint32_t*)(xs + (size_t)t5 * 128 + c0);
        uint32_t x6 = *(const uint32_t*)(xs + (size_t)t6 * 128 + c0);
        uint32_t x7 = *(const uint32_t*)(xs + (size_t)t7 * 128 + c0);
        l0 += ad; l1 += ad; l2 += ad; l3 += ad; l4 += ad; l5 += ad; l6 += ad; l7 += ad;
        l0 = l0 > 0.f ? l0 : 0.2f * l0;  l1 = l1 > 0.f ? l1 : 0.2f * l1;
        l2 = l2 > 0.f ? l2 : 0.2f * l2;  l3 = l3 > 0.f ? l3 : 0.2f * l3;
        l4 = l4 > 0.f ? l4 : 0.2f * l4;  l5 = l5 > 0.f ? l5 : 0.2f * l5;
        l6 = l6 > 0.f ? l6 : 0.2f * l6;  l7 = l7 > 0.f ? l7 : 0.2f * l7;
        l0 = ca.x < 0 ? -1e30f : l0;  l1 = ca.y < 0 ? -1e30f : l1;
        l2 = ca.z < 0 ? -1e30f : l2;  l3 = ca.w < 0 ? -1e30f : l3;
        l4 = cb.x < 0 ? -1e30f : l4;  l5 = cb.y < 0 ? -1e30f : l5;
        l6 = cb.z < 0 ? -1e30f : l6;  l7 = cb.w < 0 ? -1e30f : l7;
        float gm = fmaxf(fmaxf(fmaxf(l0, l1), fmaxf(l2, l3)),
                         fmaxf(fmaxf(l4, l5), fmaxf(l6, l7)));
        float mn = fmaxf(m, gm);
        float sc = __expf(m - mn);
        float p0 = __expf(l0 - mn), p1 = __expf(l1 - mn), p2 = __expf(l2 - mn), p3 = __expf(l3 - mn);
        float p4 = __expf(l4 - mn), p5 = __expf(l5 - mn), p6 = __expf(l6 - mn), p7 = __expf(l7 - mn);
        z  = fmaf(z,  sc, ((p0 + p1) + (p2 + p3)) + ((p4 + p5) + (p6 + p7)));
        float s0 = fmaf(p0, bflo(x0), fmaf(p1, bflo(x1), fmaf(p2, bflo(x2), p3 * bflo(x3))));
        float s1 = fmaf(p4, bflo(x4), fmaf(p5, bflo(x5), fmaf(p6, bflo(x6), p7 * bflo(x7))));
        a0 = fmaf(a0, sc, s0 + s1);
        float u0 = fmaf(p0, bfhi(x0), fmaf(p1, bfhi(x1), fmaf(p2, bfhi(x2), p3 * bfhi(x3))));
        float u1 = fmaf(p4, bfhi(x4), fmaf(p5, bfhi(x5), fmaf(p6, bfhi(x6), p7 * bfhi(x7))));
        a1 = fmaf(a1, sc, u0 + u1);
        m = mn;
    }
    if (j < je) {                                                  // one remaining group of 4
        int4 ca = *(const int4*)&col[j];
        int t0 = max(ca.x, 0), t1 = max(ca.y, 0), t2 = max(ca.z, 0), t3 = max(ca.w, 0);
        float l0 = (H == 4) ? als[t0 * 4 + hl] : als[t0];
        float l1 = (H == 4) ? als[t1 * 4 + hl] : als[t1];
        float l2 = (H == 4) ? als[t2 * 4 + hl] : als[t2];
        float l3 = (H == 4) ? als[t3 * 4 + hl] : als[t3];
        uint32_t x0 = *(const uint32_t*)(xs + (size_t)t0 * 128 + c0);
        uint32_t x1 = *(const uint32_t*)(xs + (size_t)t1 * 128 + c0);
        uint32_t x2 = *(const uint32_t*)(xs + (size_t)t2 * 128 + c0);
        uint32_t x3 = *(const uint32_t*)(xs + (size_t)t3 * 128 + c0);
        l0 += ad; l1 += ad; l2 += ad; l3 += ad;
        l0 = l0 > 0.f ? l0 : 0.2f * l0;  l1 = l1 > 0.f ? l1 : 0.2f * l1;
        l2 = l2 > 0.f ? l2 : 0.2f * l2;  l3 = l3 > 0.f ? l3 : 0.2f * l3;
        l0 = ca.x < 0 ? -1e30f : l0;  l1 = ca.y < 0 ? -1e30f : l1;
        l2 = ca.z < 0 ? -1e30f : l2;  l3 = ca.w < 0 ? -1e30f : l3;
        float gm = fmaxf(fmaxf(l0, l1), fmaxf(l2, l3));
        float mn = fmaxf(m, gm);
        float sc = __expf(m - mn);
        float p0 = __expf(l0 - mn), p1 = __expf(l1 - mn), p2 = __expf(l2 - mn), p3 = __expf(l3 - mn);
        z  = fmaf(z,  sc, (p0 + p1) + (p2 + p3));
        a0 = fmaf(a0, sc, fmaf(p0, bflo(x0), fmaf(p1, bflo(x1), fmaf(p2, bflo(x2), p3 * bflo(x3)))));
        a1 = fmaf(a1, sc, fmaf(p0, bfhi(x0), fmaf(p1, bfhi(x1), fmaf(p2, bfhi(x2), p3 * bfhi(x3)))));
        m = mn;
    }
    float inv = 1.f / (z + 1e-16f);
    float y0 = fmaf(a0 * inv, sc0v, sh0v);
    float y1 = fmaf(a1 * inv, sc1v, sh1v);
    y0 = y0 > 0.f ? y0 : expm1f(y0);             // ELU
    y1 = y1 > 0.f ? y1 : expm1f(y1);
    hv.x += y0; hv.y += y1;
    *(float2*)&h[(size_t)node * 128 + c0] = hv;  // residual, in-place (own row only)
}

// ---------------------------------------------------------------- readout scores: tiled GEMV batch
__global__ __launch_bounds__(256) void k_scores(
    const float* __restrict__ h, const float* __restrict__ w1, const float* __restrict__ b1,
    const float* __restrict__ w2, const float* __restrict__ b2,
    float* __restrict__ scores, int n)
{
    __shared__ float W1s[128 * 64];     // 32 KB
    __shared__ float As[16][132];       // padded
    __shared__ float red[4][32][4];
    const int t = threadIdx.x;
    {
        const float4* w4 = (const float4*)w1;
        float4* s4 = (float4*)W1s;
#pragma unroll
        for (int i = 0; i < 8; ++i) s4[t + i * 256] = w4[t + i * 256];
    }
    const int rg = t & 31, cg = t >> 5;     // 32 row-groups x 8 col-groups
    const int r0 = rg * 4, c0 = cg * 8;
    const int row0 = blockIdx.x * 128;
    const int ar = (t * 2) >> 2;
    const int ak0 = ((t * 2) & 3) * 4, ak1 = ((t * 2 + 1) & 3) * 4;
    float bloc[8], w2loc[8];
#pragma unroll
    for (int j = 0; j < 8; ++j) { bloc[j] = b1[c0 + j]; w2loc[j] = w2[c0 + j]; }

    float acc[4][8] = {};
    for (int kc = 0; kc < 8; ++kc) {
        __syncthreads();
        {
            float4 v0 = make_float4(0.f, 0.f, 0.f, 0.f), v1 = v0;
            int row = row0 + ar;
            if (row < n) {
                v0 = *(const float4*)&h[(size_t)row * 128 + kc * 16 + ak0];
                v1 = *(const float4*)&h[(size_t)row * 128 + kc * 16 + ak1];
            }
            As[ak0 + 0][ar] = v0.x; As[ak0 + 1][ar] = v0.y; As[ak0 + 2][ar] = v0.z; As[ak0 + 3][ar] = v0.w;
            As[ak1 + 0][ar] = v1.x; As[ak1 + 1][ar] = v1.y; As[ak1 + 2][ar] = v1.z; As[ak1 + 3][ar] = v1.w;
        }
        __syncthreads();
#pragma unroll
        for (int kk = 0; kk < 16; ++kk) {
            float a[4], w[8];
            *(float4*)&a[0] = *(const float4*)&As[kk][r0];
            *(float4*)&w[0] = *(const float4*)&W1s[(kc * 16 + kk) * 64 + c0];
            *(float4*)&w[4] = *(const float4*)&W1s[(kc * 16 + kk) * 64 + c0 + 4];
#pragma unroll
            for (int r = 0; r < 4; ++r)
#pragma unroll
                for (int j = 0; j < 8; ++j) acc[r][j] += a[r] * w[j];
        }
    }
    float part[4];
#pragma unroll
    for (int r = 0; r < 4; ++r) {
        float s = 0.f;
#pragma unroll
        for (int j = 0; j < 8; ++j) s += tanhf(acc[r][j] + bloc[j]) * w2loc[j];
        part[r] = s;
    }
#pragma unroll
    for (int r = 0; r < 4; ++r) part[r] += __shfl_xor(part[r], 32);
    const int wv = t >> 6;
    if ((t & 32) == 0) {
#pragma unroll
        for (int r = 0; r < 4; ++r) red[wv][rg][r] = part[r];
    }
    __syncthreads();
    if (t < 128) {
        int row = row0 + t;
        if (row < n) {
            float s = red[0][t >> 2][t & 3] + red[1][t >> 2][t & 3]
                    + red[2][t >> 2][t & 3] + red[3][t >> 2][t & 3];
            scores[row] = s + b2[0];
        }
    }
}
__global__ void k_graph_ptr(const int* __restrict__ batch, int* __restrict__ gptr, int n, int B) {
    int i = blockIdx.x * 256 + threadIdx.x;
    if (i >= n) return;
    int b = batch[i];
    int bp = (i == 0) ? -1 : batch[i - 1];
    for (int g = bp + 1; g <= b; ++g) gptr[g] = i;
    if (i == n - 1)
        for (int g = b + 1; g <= B; ++g) gptr[g] = n;
}
__global__ __launch_bounds__(256) void k_graph_mz(const int* __restrict__ gptr, const float* __restrict__ scores,
                                                  float* __restrict__ gmax, float* __restrict__ gz, int B) {
    int g = blockIdx.x * 4 + (threadIdx.x >> 6);
    if (g >= B) return;
    int l = threadIdx.x & 63;
    int s0 = gptr[g], s1 = gptr[g + 1];
    float m = -INFINITY;
    for (int i = s0 + l; i < s1; i += 64) m = fmaxf(m, scores[i]);
#pragma unroll
    for (int off = 32; off; off >>= 1) m = fmaxf(m, __shfl_xor(m, off));
    float z = 0.f;
    for (int i = s0 + l; i < s1; i += 64) z += __expf(scores[i] - m);
#pragma unroll
    for (int off = 32; off; off >>= 1) z += __shfl_xor(z, off);
    if (l == 0) { gmax[g] = m; gz[g] = z; }
}
__global__ void k_att(const int* __restrict__ batch, const float* __restrict__ scores,
                      const float* __restrict__ gmax, const float* __restrict__ gz,
                      float* __restrict__ att, int n) {
    int i = blockIdx.x * 256 + threadIdx.x;
    if (i >= n) return;
    int b = batch[i];
    att[i] = __expf(scores[i] - gmax[b]) / gz[b];
}
__global__ __launch_bounds__(256) void k_emb(const int* __restrict__ gptr, const float* __restrict__ att,
                                             const float* __restrict__ h, float* __restrict__ emb) {
    __shared__ float sd[16][64];
    int g = blockIdx.x >> 1, half = blockIdx.x & 1;
    int t = threadIdx.x;
    int cq = (t & 15) * 4;
    int c = half * 64 + cq;
    int p = t >> 4;                                  // 16 node-partitions
    int s0 = gptr[g], s1 = gptr[g + 1];
    float4 acc = make_float4(0.f, 0.f, 0.f, 0.f);
    for (int i = s0 + p; i < s1; i += 16) {
        float a = att[i];
        float4 hvv = *(const float4*)&h[(size_t)i * 128 + c];
        acc.x += a * hvv.x; acc.y += a * hvv.y; acc.z += a * hvv.z; acc.w += a * hvv.w;
    }
    *(float4*)&sd[p][cq] = acc;
    __syncthreads();
    if (t < 64) {
        float s = 0.f;
#pragma unroll
        for (int q = 0; q < 16; ++q) s += sd[q][t];
        emb[g * 128 + half * 64 + t] = s;
    }
}

// ---------------------------------------------------------------- launch
extern "C" void kernel_launch(void* const* d_in, const int* in_sizes, int n_in,
                              void* d_out, int out_size, void* d_ws, size_t ws_size,
                              hipStream_t stream)
{
    const float* x            = (const float*)d_in[0];
    const int*   eidx         = (const int*)d_in[1];
    const int*   batch        = (const int*)d_in[2];
    const float* W_in         = (const float*)d_in[3];
    const float* b_in         = (const float*)d_in[4];
    const float* lin_w        = (const float*)d_in[5];
    const float* att_src      = (const float*)d_in[6];
    const float* att_dst      = (const float*)d_in[7];
    const float* conv_b       = (const float*)d_in[8];
    const float* lin_w_last   = (const float*)d_in[9];
    const float* att_src_last = (const float*)d_in[10];
    const float* att_dst_last = (const float*)d_in[11];
    const float* b_last       = (const float*)d_in[12];
    const float* bn_g         = (const float*)d_in[13];
    const float* bn_b         = (const float*)d_in[14];
    const float* bn_m         = (const float*)d_in[15];
    const float* bn_v         = (const float*)d_in[16];
    const float* ro_w1        = (const float*)d_in[17];
    const float* ro_b1        = (const float*)d_in[18];
    const float* ro_w2        = (const float*)d_in[19];
    const float* ro_b2        = (const float*)d_in[20];

    const int N = in_sizes[0] / 128;
    const int E = in_sizes[1] / 2;
    const int B = 512;
    const int* esrc = eidx;
    const int* edst = eidx + E;
    const int colcap = E + 4 * N;
    const int NBKT = (N + BSZ - 1) >> BSH;           // 196 for N=100K  (<=256)
    const int cap = (E / NBKT) * 3 / 2 + 512;        // per-bucket capacity

    char* wsp = (char*)d_ws;
    size_t off = 0;
    auto alloc = [&](size_t bytes) -> void* {
        void* p = wsp + off;
        off += (bytes + 511) & ~(size_t)511;
        return p;
    };
    float*    h      = (float*)alloc((size_t)N * 128 * 4);
    uint16_t* xs     = (uint16_t*)alloc((size_t)N * 128 * 2);
    float*    als    = (float*)alloc((size_t)N * 4 * 4);
    float*    ald    = (float*)alloc((size_t)N * 4 * 4);
    float*    scores = (float*)alloc((size_t)N * 4);
    int*      rp     = (int*)alloc((size_t)(N + 1) * 4);
    int*      col    = (int*)alloc((size_t)colcap * 4);
    int*      cnt    = (int*)alloc((size_t)N * 4);
    int*      bsum   = (int*)alloc(4096);
    int*      gptr   = (int*)alloc((size_t)(B + 1) * 4);
    float*    gmax   = (float*)alloc((size_t)B * 4);
    float*    gz     = (float*)alloc((size_t)B * 4);
    float*    bnsc   = (float*)alloc(384 * 4);
    float*    bnsh   = (float*)alloc(384 * 4);
    int*      bcur   = (int*)alloc(NBKT_MAX * 4);
    uint32_t* bucketed = (uint32_t*)alloc((size_t)NBKT * cap * 4);
    (void)ws_size; (void)n_in; (void)out_size;

    float* emb = (float*)d_out;
    float* att = (float*)d_out + (size_t)B * 128;

    const int nb = (N + 1023) / 1024;
    hipLaunchKernelGGL(k_binit, dim3(1), dim3(256), 0, stream, bcur, NBKT, cap);
    hipLaunchKernelGGL(k_bucket, dim3((E + 8191) / 8192), dim3(256), 0, stream,
                       esrc, edst, bcur, bucketed, E, cap);
    hipLaunchKernelGGL(k_bcount, dim3(NBKT), dim3(256), 0, stream, bcur, bucketed, cnt, N, cap);
    hipLaunchKernelGGL(k_scan1, dim3(nb), dim3(256), 0, stream, cnt, bsum, N);
    hipLaunchKernelGGL(k_scan2, dim3(1), dim3(128), 0, stream, bsum, nb);
    hipLaunchKernelGGL(k_scan3, dim3(nb), dim3(256), 0, stream, cnt, bsum, rp, N);
    hipLaunchKernelGGL(k_bscatter, dim3(NBKT), dim3(256), 0, stream, bcur, bucketed, rp, col, N, cap);
    hipLaunchKernelGGL(k_bnprep, dim3(3), dim3(128), 0, stream, conv_b, b_last, bn_g, bn_b, bn_m, bn_v, bnsc, bnsh);

    const int ntiles = (N + 127) / 128;
    hipLaunchKernelGGL((k_gemm<0, 0>), dim3(512), dim3(256), 0, stream,
                       x, W_in, b_in, (void*)h, (const float*)nullptr, (const float*)nullptr,
                       (float*)nullptr, (float*)nullptr, N, ntiles);
    for (int i = 0; i < 2; ++i) {
        hipLaunchKernelGGL((k_gemm<4, 1>), dim3(512), dim3(256), 0, stream,
                           h, lin_w + (size_t)i * 16384, (const float*)nullptr, (void*)xs,
                           att_src + i * 128, att_dst + i * 128, als, ald, N, ntiles);
        hipLaunchKernelGGL((k_agg<4>), dim3((N + 3) / 4), dim3(256), 0, stream,
                           rp, col, als, ald, xs, bnsc + i * 128, bnsh + i * 128, h, N);
    }
    hipLaunchKernelGGL((k_gemm<1, 1>), dim3(512), dim3(256), 0, stream,
                       h, lin_w_last, (const float*)nullptr, (void*)xs,
                       att_src_last, att_dst_last, als, ald, N, ntiles);
    hipLaunchKernelGGL((k_agg<1>), dim3((N + 3) / 4), dim3(256), 0, stream,
                       rp, col, als, ald, xs, bnsc + 256, bnsh + 256, h, N);

    hipLaunchKernelGGL(k_scores, dim3(ntiles), dim3(256), 0, stream,
                       h, ro_w1, ro_b1, ro_w2, ro_b2, scores, N);
    hipLaunchKernelGGL(k_graph_ptr, dim3((N + 255) / 256), dim3(256), 0, stream, batch, gptr, N, B);
    hipLaunchKernelGGL(k_graph_mz, dim3((B + 3) / 4), dim3(256), 0, stream, gptr, scores, gmax, gz, B);
    hipLaunchKernelGGL(k_att, dim3((N + 255) / 256), dim3(256), 0, stream, batch, scores, gmax, gz, att, N);
    hipLaunchKernelGGL(k_emb, dim3(B * 2), dim3(256), 0, stream, gptr, att, h, emb);
}

// Round 5
// 686.933 us; speedup vs baseline: 1.9681x; 1.0002x over previous
//
#include <hip/hip_runtime.h>
#include <math.h>
#include <stdint.h>

#define BSZ 512
#define BSH 9
#define NBKT_MAX 256

static __device__ __forceinline__ uint32_t f2bf(float x) {
    uint32_t u = __float_as_uint(x);
    return (u + 0x7fffu + ((u >> 16) & 1u)) >> 16;   // RNE
}
static __device__ __forceinline__ float bflo(uint32_t v) { return __uint_as_float(v << 16); }
static __device__ __forceinline__ float bfhi(uint32_t v) { return __uint_as_float(v & 0xffff0000u); }

// ---------------------------------------------------------------- bucketed CSR build
__global__ void k_binit(int* __restrict__ bcur, int nbkt, int cap) {
    int t = threadIdx.x;
    if (t < nbkt) bcur[t] = t * cap;
}
// Phase A: bin edges into dst-range buckets; contiguous chunk per block-bucket.
__global__ __launch_bounds__(256) void k_bucket(const int* __restrict__ src, const int* __restrict__ dst,
                                                int* __restrict__ bcur, uint32_t* __restrict__ bucketed,
                                                int e, int cap) {
    __shared__ int hist[NBKT_MAX];
    __shared__ int cur[NBKT_MAX];
    int t = threadIdx.x;
    hist[t] = 0;
    __syncthreads();
    int base = blockIdx.x * 8192;
#pragma unroll 4
    for (int i = 0; i < 32; ++i) {
        int ei = base + i * 256 + t;
        if (ei < e) atomicAdd(&hist[dst[ei] >> BSH], 1);
    }
    __syncthreads();
    int hc = hist[t];
    cur[t] = (hc > 0) ? atomicAdd(&bcur[t], hc) : 0;
    __syncthreads();
#pragma unroll 4
    for (int i = 0; i < 32; ++i) {
        int ei = base + i * 256 + t;
        if (ei < e) {
            int d = dst[ei], s = src[ei];
            int b = d >> BSH;
            int p = atomicAdd(&cur[b], 1);
            if (p < (b + 1) * cap)
                bucketed[p] = ((uint32_t)(d & (BSZ - 1)) << 23) | (uint32_t)s;
        }
    }
}
// Phase B1: per-bucket degree count (LDS atomics only)
__global__ __launch_bounds__(256) void k_bcount(const int* __restrict__ bcur, const uint32_t* __restrict__ bucketed,
                                                int* __restrict__ cnt, int n, int cap) {
    __shared__ int lf[BSZ];
    int b = blockIdx.x, t = threadIdx.x;
    int n0 = b << BSH;
    int nn = min(BSZ, n - n0);
    for (int i = t; i < nn; i += 256) lf[i] = 0;
    __syncthreads();
    int cb = min(bcur[b] - b * cap, cap);
    const uint32_t* ba = bucketed + (size_t)b * cap;
    for (int i = t; i < cb; i += 256) atomicAdd(&lf[ba[i] >> 23], 1);
    __syncthreads();
    for (int i = t; i < nn; i += 256) cnt[n0 + i] = lf[i] + 1;    // + self loop
}
__global__ __launch_bounds__(256) void k_scan1(const int* __restrict__ cnt, int* __restrict__ bsum, int n) {
    __shared__ int sd[256];
    int base = blockIdx.x * 1024, t = threadIdx.x;
    int s = 0;
#pragma unroll
    for (int i = 0; i < 4; ++i) {
        int idx = base + t * 4 + i;
        if (idx < n) s += (cnt[idx] + 3) & ~3;       // pad4
    }
    sd[t] = s; __syncthreads();
    for (int o = 128; o; o >>= 1) {
        if (t < o) sd[t] += sd[t + o];
        __syncthreads();
    }
    if (t == 0) bsum[blockIdx.x] = sd[0];
}
__global__ void k_scan2(int* __restrict__ bsum, int nb) {
    __shared__ int sd[128];
    int t = threadIdx.x;
    int v = (t < nb) ? bsum[t] : 0;
    sd[t] = v; __syncthreads();
    for (int o = 1; o < 128; o <<= 1) {
        int u = (t >= o) ? sd[t - o] : 0;
        __syncthreads();
        sd[t] += u;
        __syncthreads();
    }
    if (t < nb) bsum[t] = sd[t] - v;  // exclusive
}
__global__ __launch_bounds__(256) void k_scan3(const int* __restrict__ cnt, const int* __restrict__ bsum,
                                               int* __restrict__ rp, int n) {
    __shared__ int sd[256];
    int base = blockIdx.x * 1024, t = threadIdx.x;
    int v[4]; int s = 0;
#pragma unroll
    for (int i = 0; i < 4; ++i) {
        int idx = base + t * 4 + i;
        v[i] = (idx < n) ? ((cnt[idx] + 3) & ~3) : 0;    // pad4
        s += v[i];
    }
    sd[t] = s; __syncthreads();
    for (int o = 1; o < 256; o <<= 1) {
        int u = (t >= o) ? sd[t - o] : 0;
        __syncthreads();
        sd[t] += u;
        __syncthreads();
    }
    int excl = sd[t] - s + bsum[blockIdx.x];
#pragma unroll
    for (int i = 0; i < 4; ++i) {
        int idx = base + t * 4 + i;
        if (idx < n) rp[idx] = excl;
        excl += v[i];
        if (idx == n - 1) rp[n] = excl;
    }
}
// Phase B2: scatter bucket edges into this bucket's private col region; self-loops + pads
__global__ __launch_bounds__(256) void k_bscatter(const int* __restrict__ bcur, const uint32_t* __restrict__ bucketed,
                                                  const int* __restrict__ rp, int* __restrict__ col,
                                                  int n, int cap) {
    __shared__ int lf[BSZ];
    __shared__ int rpl[BSZ];
    int b = blockIdx.x, t = threadIdx.x;
    int n0 = b << BSH;
    int nn = min(BSZ, n - n0);
    for (int i = t; i < nn; i += 256) {
        int r = rp[n0 + i];
        rpl[i] = r;
        lf[i] = 1;
        col[r] = n0 + i;                              // self loop at slot 0
    }
    __syncthreads();
    int cb = min(bcur[b] - b * cap, cap);
    const uint32_t* ba = bucketed + (size_t)b * cap;
    for (int i = t; i < cb; i += 256) {
        uint32_t v = ba[i];
        int ld = (int)(v >> 23), s = (int)(v & 0x7fffffu);
        int o = atomicAdd(&lf[ld], 1);
        col[rpl[ld] + o] = s;
    }
    __syncthreads();
    for (int i = t; i < nn; i += 256) {
        int c = lf[i], end = (c + 3) & ~3;
        int r = rpl[i];
        for (int j = c; j < end; ++j) col[r + j] = -1;
    }
}
// fold bias + BN into scale/shift per channel (3 layers x 128 ch)
__global__ void k_bnprep(const float* __restrict__ conv_b, const float* __restrict__ b_last,
                         const float* __restrict__ bn_g, const float* __restrict__ bn_b,
                         const float* __restrict__ bn_m, const float* __restrict__ bn_v,
                         float* __restrict__ sc, float* __restrict__ sh) {
    int i = blockIdx.x * 128 + threadIdx.x;
    if (i >= 384) return;
    int layer = i >> 7, c = i & 127;
    float bias = (layer < 2) ? conv_b[layer * 128 + c] : b_last[c];
    float s = bn_g[i] * __frsqrt_rn(bn_v[i] + 1e-5f);
    sc[i] = s;
    sh[i] = (bias - bn_m[i]) * s + bn_b[i];
}

// ---------------------------------------------------------------- GEMM 128x128 tile, 8x8 micro-tile, persistent
template <int ATT, int OBF>
__global__ __launch_bounds__(256) void k_gemm(
    const float* __restrict__ A, const float* __restrict__ W,
    const float* __restrict__ bias, void* __restrict__ outv,
    const float* __restrict__ atts, const float* __restrict__ attd,
    float* __restrict__ als, float* __restrict__ ald,
    int nrows, int ntiles)
{
    __shared__ float Ws[128 * 128];   // 64 KB (reads are 16-lane broadcasts: conflict-free)
    __shared__ float As[16][132];     // padded stride 132: As reads <=2-way (free)
    const int t = threadIdx.x;
    {
        const float4* W4 = (const float4*)W;
        float4* S4 = (float4*)Ws;
#pragma unroll
        for (int i = 0; i < 16; ++i) S4[t + i * 256] = W4[t + i * 256];
    }
    const int rg = t & 15, cg = t >> 4;
    const int r0 = rg * 8, c0 = cg * 8;
    const int wv = t >> 6;
    const int ar = (t * 2) >> 2;
    const int ak0 = ((t * 2) & 3) * 4, ak1 = ((t * 2 + 1) & 3) * 4;

    float bloc[8], avs[8], avd[8];
    if (ATT == 0) {
#pragma unroll
        for (int j = 0; j < 8; ++j) bloc[j] = bias[c0 + j];
    } else {
#pragma unroll
        for (int j = 0; j < 8; ++j) { avs[j] = atts[c0 + j]; avd[j] = attd[c0 + j]; }
    }

    for (int tile = blockIdx.x; tile < ntiles; tile += gridDim.x) {
        const int row0 = tile * 128;
        float4 v0 = make_float4(0.f, 0.f, 0.f, 0.f), v1 = v0;
        {
            int row = row0 + ar;
            if (row < nrows) {
                v0 = *(const float4*)&A[(size_t)row * 128 + ak0];
                v1 = *(const float4*)&A[(size_t)row * 128 + ak1];
            }
        }
        float acc[8][8] = {};
        for (int kc = 0; kc < 8; ++kc) {
            __syncthreads();
            As[ak0 + 0][ar] = v0.x; As[ak0 + 1][ar] = v0.y; As[ak0 + 2][ar] = v0.z; As[ak0 + 3][ar] = v0.w;
            As[ak1 + 0][ar] = v1.x; As[ak1 + 1][ar] = v1.y; As[ak1 + 2][ar] = v1.z; As[ak1 + 3][ar] = v1.w;
            __syncthreads();
            if (kc < 7) {
                int row = row0 + ar;
                v0 = make_float4(0.f, 0.f, 0.f, 0.f); v1 = v0;
                if (row < nrows) {
                    v0 = *(const float4*)&A[(size_t)row * 128 + (kc + 1) * 16 + ak0];
                    v1 = *(const float4*)&A[(size_t)row * 128 + (kc + 1) * 16 + ak1];
                }
            }
#pragma unroll
            for (int kk = 0; kk < 16; ++kk) {
                float a[8], w[8];
                *(float4*)&a[0] = *(const float4*)&As[kk][r0];
                *(float4*)&a[4] = *(const float4*)&As[kk][r0 + 4];
                *(float4*)&w[0] = *(const float4*)&Ws[(kc * 16 + kk) * 128 + c0];
                *(float4*)&w[4] = *(const float4*)&Ws[(kc * 16 + kk) * 128 + c0 + 4];
#pragma unroll
                for (int r = 0; r < 8; ++r)
#pragma unroll
                    for (int j = 0; j < 8; ++j)
                        acc[r][j] += a[r] * w[j];
            }
        }

        // ---- store
        if (OBF) {
            uint16_t* out = (uint16_t*)outv;
#pragma unroll
            for (int r = 0; r < 8; ++r) {
                int row = row0 + r0 + r;
                if (row < nrows) {
                    uint32_t up[4];
#pragma unroll
                    for (int jj = 0; jj < 4; ++jj)
                        up[jj] = (f2bf(acc[r][2 * jj + 1]) << 16) | f2bf(acc[r][2 * jj]);
                    *(uint4*)&out[(size_t)row * 128 + c0] = make_uint4(up[0], up[1], up[2], up[3]);
                }
            }
        } else {
            float* out = (float*)outv;
#pragma unroll
            for (int r = 0; r < 8; ++r) {
                int row = row0 + r0 + r;
                if (row < nrows) {
                    float o[8];
#pragma unroll
                    for (int j = 0; j < 8; ++j) o[j] = acc[r][j] + bloc[j];
                    *(float4*)&out[(size_t)row * 128 + c0]     = *(float4*)&o[0];
                    *(float4*)&out[(size_t)row * 128 + c0 + 4] = *(float4*)&o[4];
                }
            }
        }

        // ---- attention-logit epilogue
        if (ATT > 0) {
            float ps[8], pd[8];
#pragma unroll
            for (int r = 0; r < 8; ++r) {
                float s = 0.f, d = 0.f;
#pragma unroll
                for (int j = 0; j < 8; ++j) { s += acc[r][j] * avs[j]; d += acc[r][j] * avd[j]; }
                ps[r] = s; pd[r] = d;
            }
#pragma unroll
            for (int r = 0; r < 8; ++r) {
                ps[r] += __shfl_xor(ps[r], 16); ps[r] += __shfl_xor(ps[r], 32);
                pd[r] += __shfl_xor(pd[r], 16); pd[r] += __shfl_xor(pd[r], 32);
            }
            if (ATT == 4) {
                if ((t & 48) == 0) {
#pragma unroll
                    for (int r = 0; r < 8; ++r) {
                        int row = row0 + r0 + r;
                        if (row < nrows) { als[row * 4 + wv] = ps[r]; ald[row * 4 + wv] = pd[r]; }
                    }
                }
            } else {
                __shared__ float redS[4][16][8];
                __shared__ float redD[4][16][8];
                if ((t & 48) == 0) {
#pragma unroll
                    for (int r = 0; r < 8; ++r) { redS[wv][rg][r] = ps[r]; redD[wv][rg][r] = pd[r]; }
                }
                __syncthreads();
                if (t < 128) {
                    int rg2 = t >> 3, r2 = t & 7;
                    float s = redS[0][rg2][r2] + redS[1][rg2][r2] + redS[2][rg2][r2] + redS[3][rg2][r2];
                    float d = redD[0][rg2][r2] + redD[1][rg2][r2] + redD[2][rg2][r2] + redD[3][rg2][r2];
                    int row = row0 + rg2 * 8 + r2;
                    if (row < nrows) { als[row] = s; ald[row] = d; }
                }
                __syncthreads();
            }
        }
    }
}

// ---------------------------------------------------------------- GAT aggregation
// No max-subtraction (logits bounded << 88, exp cannot overflow; softmax ratio unchanged).
// Logit phase: wave-parallel — lane computes ONE edge's logit+exp for its head.
// FMA phase: p broadcast via shfl, 8 gathers in flight.
template <int H>
__global__ __launch_bounds__(256) void k_agg(
    const int* __restrict__ rp, const int* __restrict__ col,
    const float* __restrict__ als, const float* __restrict__ ald_,
    const uint16_t* __restrict__ xs, const float* __restrict__ bnsc,
    const float* __restrict__ bnsh, float* __restrict__ h, int n)
{
    constexpr int EPG = (H == 4) ? 16 : 64;      // edges per logit pass
    int node = blockIdx.x * 4 + (threadIdx.x >> 6);
    if (node >= n) return;
    int l = threadIdx.x & 63;
    int hl = (H == 4) ? (l >> 4) : 0;
    int lbase = (H == 4) ? (l & 48) : 0;
    int c0 = l * 2;
    float ad = ald_[node * H + hl];
    int jb = rp[node], je = rp[node + 1];
    float2 hv = *(const float2*)&h[(size_t)node * 128 + c0];       // residual, prefetch
    float sc0v = bnsc[c0], sc1v = bnsc[c0 + 1];
    float sh0v = bnsh[c0], sh1v = bnsh[c0 + 1];

    float z = 0.f, a0 = 0.f, a1 = 0.f;
    for (int j = jb; j < je; j += EPG) {
        // ---- logit phase: lane l handles edge j+(l & (EPG-1)) for head hl
        int e_l = j + (l & (EPG - 1));
        int s_l = (e_l < je) ? col[e_l] : -1;
        int t_l = s_l < 0 ? 0 : s_l;
        float lg = ((H == 4) ? als[t_l * 4 + hl] : als[t_l]) + ad;
        lg = fmaxf(lg, 0.2f * lg);                  // leaky_relu 0.2
        float p_l = (s_l < 0) ? 0.f : __expf(lg);
        // ---- FMA phase over real slots (ng always a multiple of 4)
        int ng = min(EPG, je - j);
        int q = 0;
        for (; q + 8 <= ng; q += 8) {
            int4 ca = *(const int4*)&col[j + q];
            int4 cb = *(const int4*)&col[j + q + 4];
            float p0 = __shfl(p_l, lbase | (q + 0));
            float p1 = __shfl(p_l, lbase | (q + 1));
            float p2 = __shfl(p_l, lbase | (q + 2));
            float p3 = __shfl(p_l, lbase | (q + 3));
            float p4 = __shfl(p_l, lbase | (q + 4));
            float p5 = __shfl(p_l, lbase | (q + 5));
            float p6 = __shfl(p_l, lbase | (q + 6));
            float p7 = __shfl(p_l, lbase | (q + 7));
            int t0 = max(ca.x, 0), t1 = max(ca.y, 0), t2 = max(ca.z, 0), t3 = max(ca.w, 0);
            int t4 = max(cb.x, 0), t5 = max(cb.y, 0), t6 = max(cb.z, 0), t7 = max(cb.w, 0);
            uint32_t x0 = *(const uint32_t*)(xs + (size_t)t0 * 128 + c0);
            uint32_t x1 = *(const uint32_t*)(xs + (size_t)t1 * 128 + c0);
            uint32_t x2 = *(const uint32_t*)(xs + (size_t)t2 * 128 + c0);
            uint32_t x3 = *(const uint32_t*)(xs + (size_t)t3 * 128 + c0);
            uint32_t x4 = *(const uint32_t*)(xs + (size_t)t4 * 128 + c0);
            uint32_t x5 = *(const uint32_t*)(xs + (size_t)t5 * 128 + c0);
            uint32_t x6 = *(const uint32_t*)(xs + (size_t)t6 * 128 + c0);
            uint32_t x7 = *(const uint32_t*)(xs + (size_t)t7 * 128 + c0);
            z += ((p0 + p1) + (p2 + p3)) + ((p4 + p5) + (p6 + p7));
            float s0 = fmaf(p0, bflo(x0), fmaf(p1, bflo(x1), fmaf(p2, bflo(x2), p3 * bflo(x3))));
            float s1 = fmaf(p4, bflo(x4), fmaf(p5, bflo(x5), fmaf(p6, bflo(x6), p7 * bflo(x7))));
            a0 += s0 + s1;
            float u0 = fmaf(p0, bfhi(x0), fmaf(p1, bfhi(x1), fmaf(p2, bfhi(x2), p3 * bfhi(x3))));
            float u1 = fmaf(p4, bfhi(x4), fmaf(p5, bfhi(x5), fmaf(p6, bfhi(x6), p7 * bfhi(x7))));
            a1 += u0 + u1;
        }
        if (q < ng) {                               // exactly 4 remaining
            int4 ca = *(const int4*)&col[j + q];
            float p0 = __shfl(p_l, lbase | (q + 0));
            float p1 = __shfl(p_l, lbase | (q + 1));
            float p2 = __shfl(p_l, lbase | (q + 2));
            float p3 = __shfl(p_l, lbase | (q + 3));
            int t0 = max(ca.x, 0), t1 = max(ca.y, 0), t2 = max(ca.z, 0), t3 = max(ca.w, 0);
            uint32_t x0 = *(const uint32_t*)(xs + (size_t)t0 * 128 + c0);
            uint32_t x1 = *(const uint32_t*)(xs + (size_t)t1 * 128 + c0);
            uint32_t x2 = *(const uint32_t*)(xs + (size_t)t2 * 128 + c0);
            uint32_t x3 = *(const uint32_t*)(xs + (size_t)t3 * 128 + c0);
            z += (p0 + p1) + (p2 + p3);
            a0 = fmaf(p0, bflo(x0), fmaf(p1, bflo(x1), fmaf(p2, bflo(x2), fmaf(p3, bflo(x3), a0))));
            a1 = fmaf(p0, bfhi(x0), fmaf(p1, bfhi(x1), fmaf(p2, bfhi(x2), fmaf(p3, bfhi(x3), a1))));
        }
    }
    float inv = 1.f / z;                            // z >= exp(self-loop logit) > 0
    float y0 = fmaf(a0 * inv, sc0v, sh0v);
    float y1 = fmaf(a1 * inv, sc1v, sh1v);
    y0 = y0 > 0.f ? y0 : expm1f(y0);                // ELU
    y1 = y1 > 0.f ? y1 : expm1f(y1);
    hv.x += y0; hv.y += y1;
    *(float2*)&h[(size_t)node * 128 + c0] = hv;     // residual, in-place (own row only)
}

// ---------------------------------------------------------------- readout scores: tiled GEMV batch
__global__ __launch_bounds__(256) void k_scores(
    const float* __restrict__ h, const float* __restrict__ w1, const float* __restrict__ b1,
    const float* __restrict__ w2, const float* __restrict__ b2,
    float* __restrict__ scores, int n)
{
    __shared__ float W1s[128 * 64];     // 32 KB
    __shared__ float As[16][132];       // padded
    __shared__ float red[4][32][4];
    const int t = threadIdx.x;
    {
        const float4* w4 = (const float4*)w1;
        float4* s4 = (float4*)W1s;
#pragma unroll
        for (int i = 0; i < 8; ++i) s4[t + i * 256] = w4[t + i * 256];
    }
    const int rg = t & 31, cg = t >> 5;     // 32 row-groups x 8 col-groups
    const int r0 = rg * 4, c0 = cg * 8;
    const int row0 = blockIdx.x * 128;
    const int ar = (t * 2) >> 2;
    const int ak0 = ((t * 2) & 3) * 4, ak1 = ((t * 2 + 1) & 3) * 4;
    float bloc[8], w2loc[8];
#pragma unroll
    for (int j = 0; j < 8; ++j) { bloc[j] = b1[c0 + j]; w2loc[j] = w2[c0 + j]; }

    float acc[4][8] = {};
    for (int kc = 0; kc < 8; ++kc) {
        __syncthreads();
        {
            float4 v0 = make_float4(0.f, 0.f, 0.f, 0.f), v1 = v0;
            int row = row0 + ar;
            if (row < n) {
                v0 = *(const float4*)&h[(size_t)row * 128 + kc * 16 + ak0];
                v1 = *(const float4*)&h[(size_t)row * 128 + kc * 16 + ak1];
            }
            As[ak0 + 0][ar] = v0.x; As[ak0 + 1][ar] = v0.y; As[ak0 + 2][ar] = v0.z; As[ak0 + 3][ar] = v0.w;
            As[ak1 + 0][ar] = v1.x; As[ak1 + 1][ar] = v1.y; As[ak1 + 2][ar] = v1.z; As[ak1 + 3][ar] = v1.w;
        }
        __syncthreads();
#pragma unroll
        for (int kk = 0; kk < 16; ++kk) {
            float a[4], w[8];
            *(float4*)&a[0] = *(const float4*)&As[kk][r0];
            *(float4*)&w[0] = *(const float4*)&W1s[(kc * 16 + kk) * 64 + c0];
            *(float4*)&w[4] = *(const float4*)&W1s[(kc * 16 + kk) * 64 + c0 + 4];
#pragma unroll
            for (int r = 0; r < 4; ++r)
#pragma unroll
                for (int j = 0; j < 8; ++j) acc[r][j] += a[r] * w[j];
        }
    }
    float part[4];
#pragma unroll
    for (int r = 0; r < 4; ++r) {
        float s = 0.f;
#pragma unroll
        for (int j = 0; j < 8; ++j) s += tanhf(acc[r][j] + bloc[j]) * w2loc[j];
        part[r] = s;
    }
#pragma unroll
    for (int r = 0; r < 4; ++r) part[r] += __shfl_xor(part[r], 32);
    const int wv = t >> 6;
    if ((t & 32) == 0) {
#pragma unroll
        for (int r = 0; r < 4; ++r) red[wv][rg][r] = part[r];
    }
    __syncthreads();
    if (t < 128) {
        int row = row0 + t;
        if (row < n) {
            float s = red[0][t >> 2][t & 3] + red[1][t >> 2][t & 3]
                    + red[2][t >> 2][t & 3] + red[3][t >> 2][t & 3];
            scores[row] = s + b2[0];
        }
    }
}
__global__ void k_graph_ptr(const int* __restrict__ batch, int* __restrict__ gptr, int n, int B) {
    int i = blockIdx.x * 256 + threadIdx.x;
    if (i >= n) return;
    int b = batch[i];
    int bp = (i == 0) ? -1 : batch[i - 1];
    for (int g = bp + 1; g <= b; ++g) gptr[g] = i;
    if (i == n - 1)
        for (int g = b + 1; g <= B; ++g) gptr[g] = n;
}
__global__ __launch_bounds__(256) void k_graph_mz(const int* __restrict__ gptr, const float* __restrict__ scores,
                                                  float* __restrict__ gmax, float* __restrict__ gz, int B) {
    int g = blockIdx.x * 4 + (threadIdx.x >> 6);
    if (g >= B) return;
    int l = threadIdx.x & 63;
    int s0 = gptr[g], s1 = gptr[g + 1];
    float m = -INFINITY;
    for (int i = s0 + l; i < s1; i += 64) m = fmaxf(m, scores[i]);
#pragma unroll
    for (int off = 32; off; off >>= 1) m = fmaxf(m, __shfl_xor(m, off));
    float z = 0.f;
    for (int i = s0 + l; i < s1; i += 64) z += __expf(scores[i] - m);
#pragma unroll
    for (int off = 32; off; off >>= 1) z += __shfl_xor(z, off);
    if (l == 0) { gmax[g] = m; gz[g] = z; }
}
__global__ void k_att(const int* __restrict__ batch, const float* __restrict__ scores,
                      const float* __restrict__ gmax, const float* __restrict__ gz,
                      float* __restrict__ att, int n) {
    int i = blockIdx.x * 256 + threadIdx.x;
    if (i >= n) return;
    int b = batch[i];
    att[i] = __expf(scores[i] - gmax[b]) / gz[b];
}
__global__ __launch_bounds__(256) void k_emb(const int* __restrict__ gptr, const float* __restrict__ att,
                                             const float* __restrict__ h, float* __restrict__ emb) {
    __shared__ float sd[16][64];
    int g = blockIdx.x >> 1, half = blockIdx.x & 1;
    int t = threadIdx.x;
    int cq = (t & 15) * 4;
    int c = half * 64 + cq;
    int p = t >> 4;                                  // 16 node-partitions
    int s0 = gptr[g], s1 = gptr[g + 1];
    float4 acc = make_float4(0.f, 0.f, 0.f, 0.f);
    for (int i = s0 + p; i < s1; i += 16) {
        float a = att[i];
        float4 hvv = *(const float4*)&h[(size_t)i * 128 + c];
        acc.x += a * hvv.x; acc.y += a * hvv.y; acc.z += a * hvv.z; acc.w += a * hvv.w;
    }
    *(float4*)&sd[p][cq] = acc;
    __syncthreads();
    if (t < 64) {
        float s = 0.f;
#pragma unroll
        for (int q = 0; q < 16; ++q) s += sd[q][t];
        emb[g * 128 + half * 64 + t] = s;
    }
}

// ---------------------------------------------------------------- launch
extern "C" void kernel_launch(void* const* d_in, const int* in_sizes, int n_in,
                              void* d_out, int out_size, void* d_ws, size_t ws_size,
                              hipStream_t stream)
{
    const float* x            = (const float*)d_in[0];
    const int*   eidx         = (const int*)d_in[1];
    const int*   batch        = (const int*)d_in[2];
    const float* W_in         = (const float*)d_in[3];
    const float* b_in         = (const float*)d_in[4];
    const float* lin_w        = (const float*)d_in[5];
    const float* att_src      = (const float*)d_in[6];
    const float* att_dst      = (const float*)d_in[7];
    const float* conv_b       = (const float*)d_in[8];
    const float* lin_w_last   = (const float*)d_in[9];
    const float* att_src_last = (const float*)d_in[10];
    const float* att_dst_last = (const float*)d_in[11];
    const float* b_last       = (const float*)d_in[12];
    const float* bn_g         = (const float*)d_in[13];
    const float* bn_b         = (const float*)d_in[14];
    const float* bn_m         = (const float*)d_in[15];
    const float* bn_v         = (const float*)d_in[16];
    const float* ro_w1        = (const float*)d_in[17];
    const float* ro_b1        = (const float*)d_in[18];
    const float* ro_w2        = (const float*)d_in[19];
    const float* ro_b2        = (const float*)d_in[20];

    const int N = in_sizes[0] / 128;
    const int E = in_sizes[1] / 2;
    const int B = 512;
    const int* esrc = eidx;
    const int* edst = eidx + E;
    const int colcap = E + 4 * N + 64;               // padded upper bound + read slack
    const int NBKT = (N + BSZ - 1) >> BSH;           // 196 for N=100K  (<=256)
    const int cap = (E / NBKT) * 3 / 2 + 512;        // per-bucket capacity

    char* wsp = (char*)d_ws;
    size_t off = 0;
    auto alloc = [&](size_t bytes) -> void* {
        void* p = wsp + off;
        off += (bytes + 511) & ~(size_t)511;
        return p;
    };
    float*    h      = (float*)alloc((size_t)N * 128 * 4);
    uint16_t* xs     = (uint16_t*)alloc((size_t)N * 128 * 2);
    float*    als    = (float*)alloc((size_t)N * 4 * 4);
    float*    ald    = (float*)alloc((size_t)N * 4 * 4);
    float*    scores = (float*)alloc((size_t)N * 4);
    int*      rp     = (int*)alloc((size_t)(N + 1) * 4);
    int*      col    = (int*)alloc((size_t)colcap * 4);
    int*      cnt    = (int*)alloc((size_t)N * 4);
    int*      bsum   = (int*)alloc(4096);
    int*      gptr   = (int*)alloc((size_t)(B + 1) * 4);
    float*    gmax   = (float*)alloc((size_t)B * 4);
    float*    gz     = (float*)alloc((size_t)B * 4);
    float*    bnsc   = (float*)alloc(384 * 4);
    float*    bnsh   = (float*)alloc(384 * 4);
    int*      bcur   = (int*)alloc(NBKT_MAX * 4);
    uint32_t* bucketed = (uint32_t*)alloc((size_t)NBKT * cap * 4);
    (void)ws_size; (void)n_in; (void)out_size;

    float* emb = (float*)d_out;
    float* att = (float*)d_out + (size_t)B * 128;

    const int nb = (N + 1023) / 1024;
    hipLaunchKernelGGL(k_binit, dim3(1), dim3(256), 0, stream, bcur, NBKT, cap);
    hipLaunchKernelGGL(k_bucket, dim3((E + 8191) / 8192), dim3(256), 0, stream,
                       esrc, edst, bcur, bucketed, E, cap);
    hipLaunchKernelGGL(k_bcount, dim3(NBKT), dim3(256), 0, stream, bcur, bucketed, cnt, N, cap);
    hipLaunchKernelGGL(k_scan1, dim3(nb), dim3(256), 0, stream, cnt, bsum, N);
    hipLaunchKernelGGL(k_scan2, dim3(1), dim3(128), 0, stream, bsum, nb);
    hipLaunchKernelGGL(k_scan3, dim3(nb), dim3(256), 0, stream, cnt, bsum, rp, N);
    hipLaunchKernelGGL(k_bscatter, dim3(NBKT), dim3(256), 0, stream, bcur, bucketed, rp, col, N, cap);
    hipLaunchKernelGGL(k_bnprep, dim3(3), dim3(128), 0, stream, conv_b, b_last, bn_g, bn_b, bn_m, bn_v, bnsc, bnsh);

    const int ntiles = (N + 127) / 128;
    hipLaunchKernelGGL((k_gemm<0, 0>), dim3(512), dim3(256), 0, stream,
                       x, W_in, b_in, (void*)h, (const float*)nullptr, (const float*)nullptr,
                       (float*)nullptr, (float*)nullptr, N, ntiles);
    for (int i = 0; i < 2; ++i) {
        hipLaunchKernelGGL((k_gemm<4, 1>), dim3(512), dim3(256), 0, stream,
                           h, lin_w + (size_t)i * 16384, (const float*)nullptr, (void*)xs,
                           att_src + i * 128, att_dst + i * 128, als, ald, N, ntiles);
        hipLaunchKernelGGL((k_agg<4>), dim3((N + 3) / 4), dim3(256), 0, stream,
                           rp, col, als, ald, xs, bnsc + i * 128, bnsh + i * 128, h, N);
    }
    hipLaunchKernelGGL((k_gemm<1, 1>), dim3(512), dim3(256), 0, stream,
                       h, lin_w_last, (const float*)nullptr, (void*)xs,
                       att_src_last, att_dst_last, als, ald, N, ntiles);
    hipLaunchKernelGGL((k_agg<1>), dim3((N + 3) / 4), dim3(256), 0, stream,
                       rp, col, als, ald, xs, bnsc + 256, bnsh + 256, h, N);

    hipLaunchKernelGGL(k_scores, dim3(ntiles), dim3(256), 0, stream,
                       h, ro_w1, ro_b1, ro_w2, ro_b2, scores, N);
    hipLaunchKernelGGL(k_graph_ptr, dim3((N + 255) / 256), dim3(256), 0, stream, batch, gptr, N, B);
    hipLaunchKernelGGL(k_graph_mz, dim3((B + 3) / 4), dim3(256), 0, stream, gptr, scores, gmax, gz, B);
    hipLaunchKernelGGL(k_att, dim3((N + 255) / 256), dim3(256), 0, stream, batch, scores, gmax, gz, att, N);
    hipLaunchKernelGGL(k_emb, dim3(B * 2), dim3(256), 0, stream, gptr, att, h, emb);
}